// Round 7
// baseline (3178.526 us; speedup 1.0000x reference)
//
#include <hip/hip_runtime.h>

#define BB 64
#define PP 33
#define IMG 1089        // 33*33
#define MM 272
#define NP1 9
#define NPATCH 81
#define KK 7
#define KK2 49
#define CATT 16
#define PADW 39
#define PIMG 1521       // 39*39

static __host__ __device__ inline int cdiv_i(int a, int b) { return (a + b - 1) / b; }

// ---------------- generic 32x32 tiled transpose: in[R][C] -> out[C][R]
__global__ __launch_bounds__(256) void k_tr(
    const float* __restrict__ in, float* __restrict__ out, int R, int C)
{
    __shared__ float t[32][33];
    int c0 = blockIdx.x * 32, r0 = blockIdx.y * 32;
    int tx = threadIdx.x, ty = threadIdx.y;
    for (int i = ty; i < 32; i += 8) {
        int r = r0 + i, c = c0 + tx;
        if (r < R && c < C) t[i][tx] = in[(size_t)r * C + c];
    }
    __syncthreads();
    for (int i = ty; i < 32; i += 8) {
        int c = c0 + i, r = r0 + tx;
        if (c < C && r < R) out[(size_t)c * R + r] = t[tx][i];
    }
}

// ---------------- fused Phi forward + duv: Phi_x/aubru live in LDS only
__global__ __launch_bounds__(320) void k_phiduv(
    const float* __restrict__ x, const float* __restrict__ PhiWT,
    const float* __restrict__ Phix_in, const float* __restrict__ ru,
    const float* __restrict__ PhiTb, const float* __restrict__ PhiTWT,
    const float* __restrict__ v_in, const float* __restrict__ conv1_w,
    const float* __restrict__ mu_p, const float* __restrict__ beta_p,
    const float* __restrict__ ls2_p,
    float* __restrict__ du, float* __restrict__ duv, float* __restrict__ wa)
{
    int b = blockIdx.x, tid = threadIdx.x;
    __shared__ float xs[IMG];
    __shared__ float ps[MM], as_[MM];
    for (int i = tid; i < IMG; i += 320) xs[i] = x[b * IMG + i];
    __syncthreads();
    if (tid < MM) {
        float mu = mu_p[0];
        const float* w = PhiWT + tid;
        float acc = 0.f;
        #pragma unroll 4
        for (int j = 0; j < IMG; ++j) acc += xs[j] * w[(size_t)j * MM];
        ps[tid] = acc;
        as_[tid] = mu * (acc - Phix_in[b * MM + tid]) - ru[b * MM + tid];
    }
    __syncthreads();
    float binv = 1.f / beta_p[0];
    float ls2 = ls2_p[0];
    for (int c = tid; c < IMG; c += 320) {
        int y = c / PP, xq = c % PP;
        float dacc = 0.f;
        #pragma unroll
        for (int dy = 0; dy < 3; ++dy) {
            int yy = y + dy - 1;
            if ((unsigned)yy >= (unsigned)PP) continue;
            #pragma unroll
            for (int dx = 0; dx < 3; ++dx) {
                int xc = xq + dx - 1;
                if ((unsigned)xc >= (unsigned)PP) continue;
                dacc += xs[yy * PP + xc] * conv1_w[dy * 3 + dx];
            }
        }
        dacc = fmaxf(dacc, 0.f);
        const float* pt = PhiTWT + c;
        float s1 = 0.f, s2 = 0.f;
        #pragma unroll 4
        for (int m = 0; m < MM; ++m) {
            float t = pt[(size_t)m * IMG];
            s1 += ps[m] * t; s2 += as_[m] * t;
        }
        int o = b * IMG + c;
        du[o] = dacc;
        duv[o] = dacc - v_in[o] * binv + ls2 * (PhiTb[o] - s1);
        wa[o] = s2;
    }
}

// ---------------- 3x3 same-pad conv, 11-px x-strip per thread (33 = 3*11)
// epil: 0 none, 1 relu, 2 soft-threshold
__global__ __launch_bounds__(256) void k_conv3x3(
    const float* __restrict__ in, const float* __restrict__ w,
    const float* __restrict__ bias, const float* __restrict__ add,
    const float* __restrict__ thr_p, float* __restrict__ out,
    int Cin, int Cout, int epil, int total)
{
    int gid = blockIdx.x * 256 + threadIdx.x;
    if (gid >= total) return;
    int s = gid % 3; int t1 = gid / 3;
    int y = t1 % PP; int t2 = t1 / PP;
    int co = t2 % Cout; int b = t2 / Cout;
    int x0 = s * 11;
    float acc[11];
    #pragma unroll
    for (int k = 0; k < 11; ++k) acc[k] = 0.f;
    const float* wb = w + (size_t)co * Cin * 9;
    const float* ib = in + (size_t)b * Cin * IMG;
    for (int ci = 0; ci < Cin; ++ci) {
        const float* img = ib + ci * IMG;
        const float* wk = wb + ci * 9;
        #pragma unroll
        for (int dy = 0; dy < 3; ++dy) {
            int yy = y + dy - 1;
            if ((unsigned)yy >= (unsigned)PP) continue;
            const float* row = img + yy * PP;
            float wA = wk[dy * 3 + 0], wB = wk[dy * 3 + 1], wC = wk[dy * 3 + 2];
            float r[13];
            #pragma unroll
            for (int i = 0; i < 13; ++i) {
                int xc = x0 - 1 + i;
                r[i] = ((unsigned)xc < (unsigned)PP) ? row[xc] : 0.f;
            }
            #pragma unroll
            for (int k = 0; k < 11; ++k)
                acc[k] += r[k] * wA + r[k + 1] * wB + r[k + 2] * wC;
        }
    }
    float bs = bias ? bias[co] : 0.f;
    float thr = (epil == 2) ? thr_p[0] : 0.f;
    int obase = (b * Cout + co) * IMG + y * PP + x0;
    #pragma unroll
    for (int k = 0; k < 11; ++k) {
        float vv = acc[k] + bs;
        if (add) vv += add[obase + k];
        if (epil == 1) vv = fmaxf(vv, 0.f);
        else if (epil == 2) {
            float av = fabsf(vv) - thr;
            vv = (vv >= 0.f ? 1.f : -1.f) * fmaxf(av, 0.f);
        }
        out[obase + k] = vv;
    }
}

// ---------------- fused tail conv (32->1 +bias +duv) + duvw elementwise; thread = pixel
__global__ __launch_bounds__(256) void k_tailduvw(
    const float* __restrict__ in, const float* __restrict__ w,
    const float* __restrict__ tail_b, const float* __restrict__ duv,
    const float* __restrict__ du, const float* __restrict__ v_in,
    const float* __restrict__ beta_p, float* __restrict__ duvw, int total)
{
    int g = blockIdx.x * 256 + threadIdx.x;
    if (g >= total) return;
    int j = g % IMG; int b = g / IMG;
    int y = j / PP, x = j % PP;
    bool vy0 = y > 0, vy2 = y < PP - 1, vx0 = x > 0, vx2 = x < PP - 1;
    const float* ib = in + (size_t)b * 32 * IMG + j;
    float acc = 0.f;
    for (int ci = 0; ci < 32; ++ci) {
        const float* p = ib + (size_t)ci * IMG;
        const float* wk = w + ci * 9;
        float a = 0.f;
        if (vy0) {
            if (vx0) a += p[-PP - 1] * wk[0];
            a += p[-PP] * wk[1];
            if (vx2) a += p[-PP + 1] * wk[2];
        }
        if (vx0) a += p[-1] * wk[3];
        a += p[0] * wk[4];
        if (vx2) a += p[1] * wk[5];
        if (vy2) {
            if (vx0) a += p[PP - 1] * wk[6];
            a += p[PP] * wk[7];
            if (vx2) a += p[PP + 1] * wk[8];
        }
        acc += a;
    }
    float beta = beta_p[0];
    float xp = duv[g] + acc + tail_b[0];
    duvw[g] = beta * du[g] - v_in[g] - beta * xp;
}

// ---------------- fused conv2 (1->1, relu) + rr + bn1a; thread = pixel
__global__ __launch_bounds__(256) void k_convrr(
    const float* __restrict__ duvw, const float* __restrict__ conv2_w,
    const float* __restrict__ r_in, const float* __restrict__ x_in,
    const float* __restrict__ xx_in, const float* __restrict__ wa,
    const float* __restrict__ uu_in,
    const float* __restrict__ theta_p, const float* __restrict__ ls_p,
    const float* __restrict__ bn_g, const float* __restrict__ bn_b,
    float* __restrict__ rr, float* __restrict__ bn1a, int total)
{
    int g = blockIdx.x * 256 + threadIdx.x;
    if (g >= total) return;
    int j = g % IMG; int b = g / IMG;
    int y = j / PP, x = j % PP;
    bool vy0 = y > 0, vy2 = y < PP - 1, vx0 = x > 0, vx2 = x < PP - 1;
    const float* p = duvw + (size_t)b * IMG + j;
    float a = 0.f;
    if (vy0) {
        if (vx0) a += p[-PP - 1] * conv2_w[0];
        a += p[-PP] * conv2_w[1];
        if (vx2) a += p[-PP + 1] * conv2_w[2];
    }
    if (vx0) a += p[-1] * conv2_w[3];
    a += p[0] * conv2_w[4];
    if (vx2) a += p[1] * conv2_w[5];
    if (vy2) {
        if (vx0) a += p[PP - 1] * conv2_w[6];
        a += p[PP] * conv2_w[7];
        if (vx2) a += p[PP + 1] * conv2_w[8];
    }
    float duvww = fmaxf(a, 0.f);
    float theta = theta_p[0], ls = ls_p[0];
    float d = duvww - r_in[g] + theta * (x_in[g] - xx_in[g]) + wa[g];
    float uu2 = uu_in[g] - ls * d;
    float rrv = uu2 - r_in[g] / theta;
    rr[g] = rrv;
    bn1a[g] = bn_g[0] * rrv * 0.9999950000374997f + bn_b[0];
}

// ---------------- Cout=1 3x3 conv + residual add; thread = pixel (convG2, convG)
__global__ __launch_bounds__(256) void k_conv1out(
    const float* __restrict__ in, const float* __restrict__ w,
    const float* __restrict__ add, float* __restrict__ out, int Cin, int total)
{
    int g = blockIdx.x * 256 + threadIdx.x;
    if (g >= total) return;
    int j = g % IMG; int b = g / IMG;
    int y = j / PP, x = j % PP;
    bool vy0 = y > 0, vy2 = y < PP - 1, vx0 = x > 0, vx2 = x < PP - 1;
    const float* ib = in + (size_t)b * Cin * IMG + j;
    float acc = 0.f;
    for (int ci = 0; ci < Cin; ++ci) {
        const float* p = ib + (size_t)ci * IMG;
        const float* wk = w + ci * 9;
        float a = 0.f;
        if (vy0) {
            if (vx0) a += p[-PP - 1] * wk[0];
            a += p[-PP] * wk[1];
            if (vx2) a += p[-PP + 1] * wk[2];
        }
        if (vx0) a += p[-1] * wk[3];
        a += p[0] * wk[4];
        if (vx2) a += p[1] * wk[5];
        if (vy2) {
            if (vx0) a += p[PP - 1] * wk[6];
            a += p[PP] * wk[7];
            if (vx2) a += p[PP + 1] * wk[8];
        }
        acc += a;
    }
    out[g] = acc + add[g];
}

// ---------------- b123 v2: thread = (b,px), z = which head (g/theta/phi); 64 ci in regs
__global__ __launch_bounds__(256) void k_b123(
    const float* __restrict__ rr3,
    const float* __restrict__ g_w, const float* __restrict__ g_b,
    const float* __restrict__ th_w, const float* __restrict__ th_b,
    const float* __restrict__ ph_w, const float* __restrict__ ph_b,
    float* __restrict__ b1p, float* __restrict__ b2p, float* __restrict__ b3p)
{
    int g = blockIdx.x * 256 + threadIdx.x;
    if (g >= BB * IMG) return;
    int sel = blockIdx.y;
    int j = g % IMG; int b = g / IMG;
    const float* w = sel == 0 ? g_w : (sel == 1 ? th_w : ph_w);
    const float* bi = sel == 0 ? g_b : (sel == 1 ? th_b : ph_b);
    float* outp = sel == 0 ? b1p : (sel == 1 ? b2p : b3p);
    const float* ip = rr3 + (size_t)b * 64 * IMG + j;
    float vals[64];
    #pragma unroll
    for (int ci = 0; ci < 64; ++ci) vals[ci] = ip[(size_t)ci * IMG];
    int y = j / PP, xq = j % PP;
    size_t obase = ((size_t)(b * CATT) * PADW + y + 3) * PADW + (xq + 3);
    #pragma unroll
    for (int co = 0; co < CATT; ++co) {
        const float* wr = w + co * 64;
        float acc = bi[co];
        #pragma unroll
        for (int ci = 0; ci < 64; ++ci) acc += vals[ci] * wr[ci];
        outp[obase + (size_t)co * PADW * PADW] = acc;
    }
}

// ---------------- scores v4: LDS q broadcast, 2 px/thread, 14-p groups (occupancy fix)
// grid: (64*5, 6), block 128
__global__ __launch_bounds__(128) void k_scores(
    const float* __restrict__ b1p, const float* __restrict__ b3p,
    float* __restrict__ scores)
{
    __shared__ float qs[KK2][16];   // 14 used, padded to 16 for b128 alignment
    int b = blockIdx.x / 5, chunk = blockIdx.x % 5;
    int p0 = blockIdx.y * 14;
    int tid = threadIdx.x;

    int pixA = chunk * 128 + tid;            // [0, 640)
    int validA = pixA < 545;
    int validB = pixA < 544;
    int pixB = validB ? pixA + 545 : pixA;
    int yA = pixA < IMG ? pixA / PP : 0, xA = pixA < IMG ? pixA % PP : 0;
    int yB = pixB / PP, xB = pixB % PP;

    float accA[14], accB[14];
    #pragma unroll
    for (int i = 0; i < 14; ++i) { accA[i] = 0.f; accB[i] = 0.f; }

    for (int c = 0; c < CATT; ++c) {
        __syncthreads();
        for (int idx = tid; idx < KK2 * 14; idx += 128) {
            int k = idx / 14, pp = idx % 14;
            int p = p0 + pp;
            float v = 0.f;
            if (p < NPATCH) {
                int py = p / NP1, px = p % NP1;
                int row = 4 * py + k / KK, col = 4 * px + k % KK;
                v = b1p[((size_t)(b * CATT + c) * PADW + row) * PADW + col];
            }
            qs[k][pp] = v;
        }
        __syncthreads();
        const float* plane = b3p + (size_t)(b * CATT + c) * PIMG;
        #pragma unroll
        for (int ky = 0; ky < KK; ++ky) {
            const float* bA = plane + (yA + ky) * PADW + xA;
            const float* bBp = plane + (yB + ky) * PADW + xB;
            float rA[KK], rB[KK];
            #pragma unroll
            for (int i = 0; i < KK; ++i) { rA[i] = bA[i]; rB[i] = bBp[i]; }
            #pragma unroll
            for (int kx = 0; kx < KK; ++kx) {
                int k = ky * KK + kx;
                const float4* q4 = (const float4*)(&qs[k][0]);
                float4 q0 = q4[0], q1 = q4[1], q2 = q4[2];
                float2 qD = *(const float2*)(&qs[k][12]);
                float a = rA[kx], b2 = rB[kx];
                accA[0] += q0.x * a;  accB[0] += q0.x * b2;
                accA[1] += q0.y * a;  accB[1] += q0.y * b2;
                accA[2] += q0.z * a;  accB[2] += q0.z * b2;
                accA[3] += q0.w * a;  accB[3] += q0.w * b2;
                accA[4] += q1.x * a;  accB[4] += q1.x * b2;
                accA[5] += q1.y * a;  accB[5] += q1.y * b2;
                accA[6] += q1.z * a;  accB[6] += q1.z * b2;
                accA[7] += q1.w * a;  accB[7] += q1.w * b2;
                accA[8] += q2.x * a;  accB[8] += q2.x * b2;
                accA[9] += q2.y * a;  accB[9] += q2.y * b2;
                accA[10] += q2.z * a; accB[10] += q2.z * b2;
                accA[11] += q2.w * a; accB[11] += q2.w * b2;
                accA[12] += qD.x * a; accB[12] += qD.x * b2;
                accA[13] += qD.y * a; accB[13] += qD.y * b2;
            }
        }
    }
    #pragma unroll
    for (int pp = 0; pp < 14; ++pp) {
        int p = p0 + pp;
        if (p >= NPATCH) break;
        size_t rowb = (size_t)(b * NPATCH + p) * IMG;
        if (validA) scores[rowb + pixA] = accA[pp];
        if (validB) scores[rowb + pixA + 545] = accB[pp];
    }
}

// ---------------- row softmax over 1089 (in-place), scale 10
__global__ __launch_bounds__(256) void k_softmax(float* __restrict__ sc)
{
    int row = blockIdx.x;
    float* p = sc + (size_t)row * IMG;
    __shared__ float red[256];
    int tid = threadIdx.x;
    float v[5];
    float m = -1e30f;
    #pragma unroll
    for (int i = 0; i < 5; ++i) {
        int idx = tid + i * 256;
        v[i] = (idx < IMG) ? p[idx] : -1e30f;
        m = fmaxf(m, v[i]);
    }
    red[tid] = m; __syncthreads();
    for (int s = 128; s > 0; s >>= 1) { if (tid < s) red[tid] = fmaxf(red[tid], red[tid + s]); __syncthreads(); }
    m = red[0]; __syncthreads();
    float sum = 0.f;
    #pragma unroll
    for (int i = 0; i < 5; ++i) {
        int idx = tid + i * 256;
        float e = (idx < IMG) ? __expf(10.f * (v[i] - m)) : 0.f;
        v[i] = e; sum += e;
    }
    red[tid] = sum; __syncthreads();
    for (int s = 128; s > 0; s >>= 1) { if (tid < s) red[tid] += red[tid + s]; __syncthreads(); }
    float inv = 1.f / red[0];
    #pragma unroll
    for (int i = 0; i < 5; ++i) {
        int idx = tid + i * 256;
        if (idx < IMG) p[idx] = v[i] * inv;
    }
}

// ---------------- agg v4: atomic-free, 9 p-groups, wave-uniform attn reads
__global__ __launch_bounds__(256) void k_agg(
    const float* __restrict__ attn, const float* __restrict__ b2p,
    float* __restrict__ agg)
{
    int b = blockIdx.x;
    int c = blockIdx.y * 4 + (threadIdx.x >> 6);
    int k = threadIdx.x & 63;
    int p0 = blockIdx.z * 9;
    if (k >= KK2) return;
    int oy = k / KK, ox = k % KK;
    const float* vp = b2p + ((size_t)(b * CATT + c) * PADW + oy) * PADW + ox;
    const float* ap = attn + (size_t)(b * NPATCH + p0) * IMG;
    float acc[9];
    #pragma unroll
    for (int p = 0; p < 9; ++p) acc[p] = 0.f;
    for (int y = 0; y < PP; ++y) {
        const float* ar = ap + y * PP;
        const float* vr = vp + y * PADW;
        #pragma unroll 1
        for (int x = 0; x < 32; x += 4) {
            float v0 = vr[x], v1 = vr[x + 1], v2 = vr[x + 2], v3 = vr[x + 3];
            #pragma unroll
            for (int p = 0; p < 9; ++p) {
                const float* a = ar + (size_t)p * IMG + x;
                acc[p] += a[0] * v0 + a[1] * v1 + a[2] * v2 + a[3] * v3;
            }
        }
        {
            float v0 = vr[32];
            #pragma unroll
            for (int p = 0; p < 9; ++p) acc[p] += ar[(size_t)p * IMG + 32] * v0;
        }
    }
    #pragma unroll
    for (int p = 0; p < 9; ++p)
        agg[(size_t)((b * NPATCH + p0 + p) * CATT + c) * KK2 + k] = acc[p];
}

// ---------------- fold + count normalize + crop -> y_att[b,c,33,33]
__global__ __launch_bounds__(256) void k_fold(
    const float* __restrict__ agg, float* __restrict__ y_att, int total)
{
    int g = blockIdx.x * 256 + threadIdx.x;
    if (g >= total) return;
    int j = g % IMG; int t = g / IMG; int c = t % CATT; int b = t / CATT;
    int y = j / PP, x = j % PP;
    int yp = y + 3, xp = x + 3;
    int pylo = (yp - 3) >> 2; int pyhi = min(8, yp >> 2);
    int pxlo = (xp - 3) >> 2; int pxhi = min(8, xp >> 2);
    float sum = 0.f;
    int cnt = (pyhi - pylo + 1) * (pxhi - pxlo + 1);
    for (int py = pylo; py <= pyhi; ++py) {
        int ky = yp - 4 * py;
        for (int px = pxlo; px <= pxhi; ++px) {
            int kx = xp - 4 * px;
            sum += agg[(size_t)((b * NPATCH + py * NP1 + px) * CATT + c) * KK2 + ky * KK + kx];
        }
    }
    y_att[(size_t)(b * CATT + c) * IMG + j] = sum / (float)cnt;
}

// ---------------- 1x1 conv generic (W: 16->64, +bias, +rr3 residual)
__global__ __launch_bounds__(256) void k_conv1x1(
    const float* __restrict__ in, const float* __restrict__ w,
    const float* __restrict__ bias, const float* __restrict__ add,
    float* __restrict__ out, int Cin, int Cout, int total)
{
    int g = blockIdx.x * 256 + threadIdx.x;
    if (g >= total) return;
    int j = g % IMG; int t = g / IMG; int co = t % Cout; int b = t / Cout;
    const float* ip = in + (size_t)b * Cin * IMG + j;
    const float* wr = w + co * Cin;
    float acc = bias ? bias[co] : 0.f;
    #pragma unroll 4
    for (int ci = 0; ci < Cin; ++ci) acc += ip[(size_t)ci * IMG] * wr[ci];
    if (add) acc += add[g];
    out[g] = acc;
}

extern "C" void kernel_launch(void* const* d_in, const int* in_sizes, int n_in,
                              void* d_out, int out_size, void* d_ws, size_t ws_size,
                              hipStream_t stream)
{
    (void)in_sizes; (void)n_in; (void)out_size; (void)ws_size;
    const float* x      = (const float*)d_in[0];
    const float* PhiTb  = (const float*)d_in[1];
    const float* v_in   = (const float*)d_in[2];
    const float* r_in   = (const float*)d_in[3];
    const float* ru     = (const float*)d_in[4];
    const float* xx_in  = (const float*)d_in[5];
    const float* uu_in  = (const float*)d_in[6];
    const float* Phix   = (const float*)d_in[7];
    const float* PhiW   = (const float*)d_in[8];
    const float* PhiTW  = (const float*)d_in[9];
    const float* ls_p   = (const float*)d_in[10];
    const float* ls2_p  = (const float*)d_in[11];
    const float* thr_p  = (const float*)d_in[12];
    const float* beta_p = (const float*)d_in[13];
    const float* mu_p   = (const float*)d_in[14];
    const float* theta_p= (const float*)d_in[15];
    const float* conv1_w  = (const float*)d_in[16];
    const float* conv2_w  = (const float*)d_in[17];
    const float* convG1_w = (const float*)d_in[18];
    const float* convD_w  = (const float*)d_in[19];
    const float* conv1f_w = (const float*)d_in[20];
    const float* conv2f_w = (const float*)d_in[21];
    const float* conv1b_w = (const float*)d_in[22];
    const float* conv2b_w = (const float*)d_in[23];
    const float* convG_w  = (const float*)d_in[24];
    const float* convG2_w = (const float*)d_in[25];
    const float* head_w = (const float*)d_in[26];
    const float* head_b = (const float*)d_in[27];
    const float* tail_w = (const float*)d_in[28];
    const float* tail_b = (const float*)d_in[29];
    const float* rb1_w1 = (const float*)d_in[30];
    const float* rb1_b1 = (const float*)d_in[31];
    const float* rb1_w2 = (const float*)d_in[32];
    const float* rb1_b2 = (const float*)d_in[33];
    const float* rb2_w1 = (const float*)d_in[34];
    const float* rb2_b1 = (const float*)d_in[35];
    const float* rb2_w2 = (const float*)d_in[36];
    const float* rb2_b2 = (const float*)d_in[37];
    const float* g_w  = (const float*)d_in[38];
    const float* g_b  = (const float*)d_in[39];
    const float* th_w = (const float*)d_in[40];
    const float* th_b = (const float*)d_in[41];
    const float* ph_w = (const float*)d_in[42];
    const float* ph_b = (const float*)d_in[43];
    const float* W_w  = (const float*)d_in[44];
    const float* W_b  = (const float*)d_in[45];
    const float* bn_g = (const float*)d_in[46];
    const float* bn_b = (const float*)d_in[47];

    const int NSM = BB * IMG;            // 69696
    float* ws = (float*)d_ws;
    float* du    = ws;
    float* Phi_x = du + NSM;             // unused (kept for layout stability)
    float* aubru = Phi_x + BB * MM;      // unused
    float* duv   = aubru + BB * MM;
    float* wa    = duv + NSM;
    float* duvw  = wa + NSM;
    float* rr    = duvw + NSM;
    float* bn1a  = rr + NSM;
    float* rr_nl = bn1a + NSM;
    float* xp    = rr_nl + NSM;          // unused
    float* duvww = xp + NSM;             // unused
    float* rr3   = duvww + NSM;                        // B*64*IMG
    float* R7    = rr3 + (size_t)BB * 64 * IMG;
    float* buf_a = R7;
    float* buf_b = R7 + (size_t)BB * 32 * IMG;
    float* agg   = R7;                                  // reuse after bufs dead
    float* b1p   = R7 + (size_t)2 * BB * 32 * IMG;
    float* b2p   = b1p + (size_t)BB * CATT * PIMG;
    float* b3p   = b2p + (size_t)BB * CATT * PIMG;
    float* y_att = b1p;                                 // reuse
    float* scores= b3p + (size_t)BB * CATT * PIMG;      // B*81*IMG
    float* ybuf  = scores;                              // reuse
    float* PhiWT = scores + (size_t)BB * NPATCH * IMG;  // [1089][272]
    float* PhiTWT= PhiWT + (size_t)MM * IMG;            // [272][1089]

    const int tot32 = BB * 32 * PP * 3;   // strip-11 threads
    const int tot64 = BB * 64 * PP * 3;

    hipMemsetAsync(b1p, 0, (size_t)3 * BB * CATT * PIMG * sizeof(float), stream);

    {
        dim3 blk(32, 8);
        dim3 g1(cdiv_i(IMG, 32), cdiv_i(MM, 32));
        k_tr<<<g1, blk, 0, stream>>>(PhiW, PhiWT, MM, IMG);
        dim3 g2(cdiv_i(MM, 32), cdiv_i(IMG, 32));
        k_tr<<<g2, blk, 0, stream>>>(PhiTW, PhiTWT, IMG, MM);
    }

    k_phiduv<<<BB, 320, 0, stream>>>(x, PhiWT, Phix, ru, PhiTb, PhiTWT, v_in, conv1_w,
                                     mu_p, beta_p, ls2_p, du, duv, wa);

    // denoiser: head + 2 resblocks, then fused tail+duvw, fused conv2+rr
    k_conv3x3<<<cdiv_i(tot32,256),256,0,stream>>>(duv,  head_w, head_b, nullptr, nullptr, buf_a, 1, 32, 0, tot32);
    k_conv3x3<<<cdiv_i(tot32,256),256,0,stream>>>(buf_a, rb1_w1, rb1_b1, nullptr, nullptr, buf_b, 32, 32, 1, tot32);
    k_conv3x3<<<cdiv_i(tot32,256),256,0,stream>>>(buf_b, rb1_w2, rb1_b2, buf_a,  nullptr, buf_a, 32, 32, 0, tot32);
    k_conv3x3<<<cdiv_i(tot32,256),256,0,stream>>>(buf_a, rb2_w1, rb2_b1, nullptr, nullptr, buf_b, 32, 32, 1, tot32);
    k_conv3x3<<<cdiv_i(tot32,256),256,0,stream>>>(buf_b, rb2_w2, rb2_b2, buf_a,  nullptr, buf_a, 32, 32, 0, tot32);
    k_tailduvw<<<cdiv_i(NSM,256),256,0,stream>>>(buf_a, tail_w, tail_b, duv, du, v_in, beta_p, duvw, NSM);
    k_convrr<<<cdiv_i(NSM,256),256,0,stream>>>(duvw, conv2_w, r_in, x, xx_in, wa, uu_in,
                                               theta_p, ls_p, bn_g, bn_b, rr, bn1a, NSM);
    k_conv3x3<<<cdiv_i(tot64,256),256,0,stream>>>(bn1a, convG1_w, nullptr, nullptr, nullptr, rr3, 1, 64, 1, tot64);

    // attention
    {
        dim3 gb(cdiv_i(BB * IMG, 256), 3);
        k_b123<<<gb, 256, 0, stream>>>(rr3, g_w, g_b, th_w, th_b, ph_w, ph_b, b1p, b2p, b3p);
    }
    {
        dim3 gs(BB * 5, 6);
        k_scores<<<gs, 128, 0, stream>>>(b1p, b3p, scores);
    }
    k_softmax<<<BB * NPATCH, 256, 0, stream>>>(scores);
    {
        dim3 ga(BB, 4, 9);
        k_agg<<<ga, 256, 0, stream>>>(scores, b2p, agg);
    }
    k_fold<<<cdiv_i(BB*CATT*IMG,256),256,0,stream>>>(agg, y_att, BB*CATT*IMG);
    k_conv1x1<<<cdiv_i(BB*64*IMG,256),256,0,stream>>>(y_att, W_w, W_b, rr3, ybuf, 16, 64, BB*64*IMG);
    k_conv1out<<<cdiv_i(NSM,256),256,0,stream>>>(ybuf, convG2_w, rr, rr_nl, 64, NSM);

    // ISTA soft-threshold stage
    k_conv3x3<<<cdiv_i(tot32,256),256,0,stream>>>(rr_nl, convD_w,  nullptr, nullptr, nullptr, buf_a, 1, 32, 0, tot32);
    k_conv3x3<<<cdiv_i(tot32,256),256,0,stream>>>(buf_a, conv1f_w, nullptr, nullptr, nullptr, buf_b, 32, 32, 1, tot32);
    k_conv3x3<<<cdiv_i(tot32,256),256,0,stream>>>(buf_b, conv2f_w, nullptr, nullptr, thr_p,   buf_a, 32, 32, 2, tot32);
    k_conv3x3<<<cdiv_i(tot32,256),256,0,stream>>>(buf_a, conv1b_w, nullptr, nullptr, nullptr, buf_b, 32, 32, 1, tot32);
    k_conv3x3<<<cdiv_i(tot32,256),256,0,stream>>>(buf_b, conv2b_w, nullptr, nullptr, nullptr, buf_a, 32, 32, 0, tot32);
    k_conv1out<<<cdiv_i(NSM,256),256,0,stream>>>(buf_a, convG_w, rr_nl, (float*)d_out, 32, NSM);
}

// Round 8
// 1425.558 us; speedup vs baseline: 2.2297x; 2.2297x over previous
//
#include <hip/hip_runtime.h>

#define BB 64
#define PP 33
#define IMG 1089        // 33*33
#define MM 272
#define NP1 9
#define NPATCH 81
#define KK 7
#define KK2 49
#define CATT 16
#define PADW 39
#define PIMG 1521       // 39*39

static __host__ __device__ inline int cdiv_i(int a, int b) { return (a + b - 1) / b; }

// ---------------- generic 32x32 tiled transpose: in[R][C] -> out[C][R]
__global__ __launch_bounds__(256) void k_tr(
    const float* __restrict__ in, float* __restrict__ out, int R, int C)
{
    __shared__ float t[32][33];
    int c0 = blockIdx.x * 32, r0 = blockIdx.y * 32;
    int tx = threadIdx.x, ty = threadIdx.y;
    for (int i = ty; i < 32; i += 8) {
        int r = r0 + i, c = c0 + tx;
        if (r < R && c < C) t[i][tx] = in[(size_t)r * C + c];
    }
    __syncthreads();
    for (int i = ty; i < 32; i += 8) {
        int c = c0 + i, r = r0 + tx;
        if (c < C && r < R) out[(size_t)c * R + r] = t[tx][i];
    }
}

// ---------------- fused Phi forward + duv: Phi_x/aubru live in LDS only
__global__ __launch_bounds__(320) void k_phiduv(
    const float* __restrict__ x, const float* __restrict__ PhiWT,
    const float* __restrict__ Phix_in, const float* __restrict__ ru,
    const float* __restrict__ PhiTb, const float* __restrict__ PhiTWT,
    const float* __restrict__ v_in, const float* __restrict__ conv1_w,
    const float* __restrict__ mu_p, const float* __restrict__ beta_p,
    const float* __restrict__ ls2_p,
    float* __restrict__ du, float* __restrict__ duv, float* __restrict__ wa)
{
    int b = blockIdx.x, tid = threadIdx.x;
    __shared__ float xs[IMG];
    __shared__ float ps[MM], as_[MM];
    for (int i = tid; i < IMG; i += 320) xs[i] = x[b * IMG + i];
    __syncthreads();
    if (tid < MM) {
        float mu = mu_p[0];
        const float* w = PhiWT + tid;
        float acc = 0.f;
        #pragma unroll 4
        for (int j = 0; j < IMG; ++j) acc += xs[j] * w[(size_t)j * MM];
        ps[tid] = acc;
        as_[tid] = mu * (acc - Phix_in[b * MM + tid]) - ru[b * MM + tid];
    }
    __syncthreads();
    float binv = 1.f / beta_p[0];
    float ls2 = ls2_p[0];
    for (int c = tid; c < IMG; c += 320) {
        int y = c / PP, xq = c % PP;
        float dacc = 0.f;
        #pragma unroll
        for (int dy = 0; dy < 3; ++dy) {
            int yy = y + dy - 1;
            if ((unsigned)yy >= (unsigned)PP) continue;
            #pragma unroll
            for (int dx = 0; dx < 3; ++dx) {
                int xc = xq + dx - 1;
                if ((unsigned)xc >= (unsigned)PP) continue;
                dacc += xs[yy * PP + xc] * conv1_w[dy * 3 + dx];
            }
        }
        dacc = fmaxf(dacc, 0.f);
        const float* pt = PhiTWT + c;
        float s1 = 0.f, s2 = 0.f;
        #pragma unroll 4
        for (int m = 0; m < MM; ++m) {
            float t = pt[(size_t)m * IMG];
            s1 += ps[m] * t; s2 += as_[m] * t;
        }
        int o = b * IMG + c;
        du[o] = dacc;
        duv[o] = dacc - v_in[o] * binv + ls2 * (PhiTb[o] - s1);
        wa[o] = s2;
    }
}

// ---------------- 3x3 same-pad conv, 11-px x-strip per thread (kept for Cin=1 convs)
__global__ __launch_bounds__(256) void k_conv3x3(
    const float* __restrict__ in, const float* __restrict__ w,
    const float* __restrict__ bias, const float* __restrict__ add,
    const float* __restrict__ thr_p, float* __restrict__ out,
    int Cin, int Cout, int epil, int total)
{
    int gid = blockIdx.x * 256 + threadIdx.x;
    if (gid >= total) return;
    int s = gid % 3; int t1 = gid / 3;
    int y = t1 % PP; int t2 = t1 / PP;
    int co = t2 % Cout; int b = t2 / Cout;
    int x0 = s * 11;
    float acc[11];
    #pragma unroll
    for (int k = 0; k < 11; ++k) acc[k] = 0.f;
    const float* wb = w + (size_t)co * Cin * 9;
    const float* ib = in + (size_t)b * Cin * IMG;
    for (int ci = 0; ci < Cin; ++ci) {
        const float* img = ib + ci * IMG;
        const float* wk = wb + ci * 9;
        #pragma unroll
        for (int dy = 0; dy < 3; ++dy) {
            int yy = y + dy - 1;
            if ((unsigned)yy >= (unsigned)PP) continue;
            const float* row = img + yy * PP;
            float wA = wk[dy * 3 + 0], wB = wk[dy * 3 + 1], wC = wk[dy * 3 + 2];
            float r[13];
            #pragma unroll
            for (int i = 0; i < 13; ++i) {
                int xc = x0 - 1 + i;
                r[i] = ((unsigned)xc < (unsigned)PP) ? row[xc] : 0.f;
            }
            #pragma unroll
            for (int k = 0; k < 11; ++k)
                acc[k] += r[k] * wA + r[k + 1] * wB + r[k + 2] * wC;
        }
    }
    float bs = bias ? bias[co] : 0.f;
    float thr = (epil == 2) ? thr_p[0] : 0.f;
    int obase = (b * Cout + co) * IMG + y * PP + x0;
    #pragma unroll
    for (int k = 0; k < 11; ++k) {
        float vv = acc[k] + bs;
        if (add) vv += add[obase + k];
        if (epil == 1) vv = fmaxf(vv, 0.f);
        else if (epil == 2) {
            float av = fabsf(vv) - thr;
            vv = (vv >= 0.f ? 1.f : -1.f) * fmaxf(av, 0.f);
        }
        out[obase + k] = vv;
    }
}

// ---------------- conv32: 32->32 3x3, LDS-banded. block=(b, 3-row band), 256 thr = 32co x 8slot.
// LDS: [32ci][5 rows][36 cols], col-shifted by +1 (cc holds input col cc-1; zeros at borders).
// epil: 0 none, 1 relu, 2 soft-threshold
__global__ __launch_bounds__(256) void k_conv32(
    const float* __restrict__ in, const float* __restrict__ w,
    const float* __restrict__ bias, const float* __restrict__ add,
    const float* __restrict__ thr_p, float* __restrict__ out, int epil)
{
    __shared__ float s[32][5][36];
    int b = blockIdx.x;
    int r0 = blockIdx.y * 3;
    // stage 5-row halo for all 32 input channels
    for (int idx = threadIdx.x; idx < 32 * 5 * 36; idx += 256) {
        int ci = idx / 180; int rem = idx % 180; int rr = rem / 36; int cc = rem % 36;
        int row = r0 - 1 + rr; int col = cc - 1;
        float v = 0.f;
        if ((unsigned)row < (unsigned)PP && (unsigned)col < (unsigned)PP)
            v = in[((size_t)b * 32 + ci) * IMG + row * PP + col];
        s[ci][rr][cc] = v;
    }
    __syncthreads();
    int co = threadIdx.x >> 3;     // 0..31
    int sl = threadIdx.x & 7;      // 0..7
    int c0 = sl * 4;               // output cols c0..c0+3 (+col 32 for sl==7)
    bool wide = (sl == 7);
    float acc[3][5];
    #pragma unroll
    for (int i = 0; i < 3; ++i)
        #pragma unroll
        for (int j = 0; j < 5; ++j) acc[i][j] = 0.f;
    const float* wb = w + (size_t)co * 32 * 9;
    for (int ci = 0; ci < 32; ++ci) {
        const float* wk = wb + ci * 9;
        float w0 = wk[0], w1 = wk[1], w2 = wk[2], w3 = wk[3], w4 = wk[4],
              w5 = wk[5], w6 = wk[6], w7 = wk[7], w8 = wk[8];
        float wr[5][8];
        #pragma unroll
        for (int rr = 0; rr < 5; ++rr) {
            float4 a = *(const float4*)&s[ci][rr][c0];
            float4 bq = *(const float4*)&s[ci][rr][c0 + 4];
            wr[rr][0] = a.x;  wr[rr][1] = a.y;  wr[rr][2] = a.z;  wr[rr][3] = a.w;
            wr[rr][4] = bq.x; wr[rr][5] = bq.y; wr[rr][6] = bq.z; wr[rr][7] = bq.w;
        }
        #pragma unroll
        for (int orow = 0; orow < 3; ++orow) {
            #pragma unroll
            for (int j = 0; j < 5; ++j) {
                if (j < 4 || wide) {
                    acc[orow][j] += wr[orow][j] * w0 + wr[orow][j + 1] * w1 + wr[orow][j + 2] * w2
                                  + wr[orow + 1][j] * w3 + wr[orow + 1][j + 1] * w4 + wr[orow + 1][j + 2] * w5
                                  + wr[orow + 2][j] * w6 + wr[orow + 2][j + 1] * w7 + wr[orow + 2][j + 2] * w8;
                }
            }
        }
    }
    float bs = bias ? bias[co] : 0.f;
    float thr = (epil == 2) ? thr_p[0] : 0.f;
    #pragma unroll
    for (int orow = 0; orow < 3; ++orow) {
        int gr = (b * 32 + co) * IMG + (r0 + orow) * PP + c0;
        #pragma unroll
        for (int j = 0; j < 5; ++j) {
            if (j < 4 || wide) {
                float vv = acc[orow][j] + bs;
                if (add) vv += add[gr + j];
                if (epil == 1) vv = fmaxf(vv, 0.f);
                else if (epil == 2) {
                    float av = fabsf(vv) - thr;
                    vv = (vv >= 0.f ? 1.f : -1.f) * fmaxf(av, 0.f);
                }
                out[gr + j] = vv;
            }
        }
    }
}

// ---------------- fused tail conv (32->1 +bias +duv) + duvw elementwise; thread = pixel
__global__ __launch_bounds__(256) void k_tailduvw(
    const float* __restrict__ in, const float* __restrict__ w,
    const float* __restrict__ tail_b, const float* __restrict__ duv,
    const float* __restrict__ du, const float* __restrict__ v_in,
    const float* __restrict__ beta_p, float* __restrict__ duvw, int total)
{
    int g = blockIdx.x * 256 + threadIdx.x;
    if (g >= total) return;
    int j = g % IMG; int b = g / IMG;
    int y = j / PP, x = j % PP;
    bool vy0 = y > 0, vy2 = y < PP - 1, vx0 = x > 0, vx2 = x < PP - 1;
    const float* ib = in + (size_t)b * 32 * IMG + j;
    float acc = 0.f;
    for (int ci = 0; ci < 32; ++ci) {
        const float* p = ib + (size_t)ci * IMG;
        const float* wk = w + ci * 9;
        float a = 0.f;
        if (vy0) {
            if (vx0) a += p[-PP - 1] * wk[0];
            a += p[-PP] * wk[1];
            if (vx2) a += p[-PP + 1] * wk[2];
        }
        if (vx0) a += p[-1] * wk[3];
        a += p[0] * wk[4];
        if (vx2) a += p[1] * wk[5];
        if (vy2) {
            if (vx0) a += p[PP - 1] * wk[6];
            a += p[PP] * wk[7];
            if (vx2) a += p[PP + 1] * wk[8];
        }
        acc += a;
    }
    float beta = beta_p[0];
    float xp = duv[g] + acc + tail_b[0];
    duvw[g] = beta * du[g] - v_in[g] - beta * xp;
}

// ---------------- fused conv2 (1->1, relu) + rr + bn1a; thread = pixel
__global__ __launch_bounds__(256) void k_convrr(
    const float* __restrict__ duvw, const float* __restrict__ conv2_w,
    const float* __restrict__ r_in, const float* __restrict__ x_in,
    const float* __restrict__ xx_in, const float* __restrict__ wa,
    const float* __restrict__ uu_in,
    const float* __restrict__ theta_p, const float* __restrict__ ls_p,
    const float* __restrict__ bn_g, const float* __restrict__ bn_b,
    float* __restrict__ rr, float* __restrict__ bn1a, int total)
{
    int g = blockIdx.x * 256 + threadIdx.x;
    if (g >= total) return;
    int j = g % IMG; int b = g / IMG;
    int y = j / PP, x = j % PP;
    bool vy0 = y > 0, vy2 = y < PP - 1, vx0 = x > 0, vx2 = x < PP - 1;
    const float* p = duvw + (size_t)b * IMG + j;
    float a = 0.f;
    if (vy0) {
        if (vx0) a += p[-PP - 1] * conv2_w[0];
        a += p[-PP] * conv2_w[1];
        if (vx2) a += p[-PP + 1] * conv2_w[2];
    }
    if (vx0) a += p[-1] * conv2_w[3];
    a += p[0] * conv2_w[4];
    if (vx2) a += p[1] * conv2_w[5];
    if (vy2) {
        if (vx0) a += p[PP - 1] * conv2_w[6];
        a += p[PP] * conv2_w[7];
        if (vx2) a += p[PP + 1] * conv2_w[8];
    }
    float duvww = fmaxf(a, 0.f);
    float theta = theta_p[0], ls = ls_p[0];
    float d = duvww - r_in[g] + theta * (x_in[g] - xx_in[g]) + wa[g];
    float uu2 = uu_in[g] - ls * d;
    float rrv = uu2 - r_in[g] / theta;
    rr[g] = rrv;
    bn1a[g] = bn_g[0] * rrv * 0.9999950000374997f + bn_b[0];
}

// ---------------- Cout=1 3x3 conv + residual add; thread = pixel (convG2, convG)
__global__ __launch_bounds__(256) void k_conv1out(
    const float* __restrict__ in, const float* __restrict__ w,
    const float* __restrict__ add, float* __restrict__ out, int Cin, int total)
{
    int g = blockIdx.x * 256 + threadIdx.x;
    if (g >= total) return;
    int j = g % IMG; int b = g / IMG;
    int y = j / PP, x = j % PP;
    bool vy0 = y > 0, vy2 = y < PP - 1, vx0 = x > 0, vx2 = x < PP - 1;
    const float* ib = in + (size_t)b * Cin * IMG + j;
    float acc = 0.f;
    for (int ci = 0; ci < Cin; ++ci) {
        const float* p = ib + (size_t)ci * IMG;
        const float* wk = w + ci * 9;
        float a = 0.f;
        if (vy0) {
            if (vx0) a += p[-PP - 1] * wk[0];
            a += p[-PP] * wk[1];
            if (vx2) a += p[-PP + 1] * wk[2];
        }
        if (vx0) a += p[-1] * wk[3];
        a += p[0] * wk[4];
        if (vx2) a += p[1] * wk[5];
        if (vy2) {
            if (vx0) a += p[PP - 1] * wk[6];
            a += p[PP] * wk[7];
            if (vx2) a += p[PP + 1] * wk[8];
        }
        acc += a;
    }
    out[g] = acc + add[g];
}

// ---------------- b123 v2: thread = (b,px), z = which head (g/theta/phi); 64 ci in regs
__global__ __launch_bounds__(256) void k_b123(
    const float* __restrict__ rr3,
    const float* __restrict__ g_w, const float* __restrict__ g_b,
    const float* __restrict__ th_w, const float* __restrict__ th_b,
    const float* __restrict__ ph_w, const float* __restrict__ ph_b,
    float* __restrict__ b1p, float* __restrict__ b2p, float* __restrict__ b3p)
{
    int g = blockIdx.x * 256 + threadIdx.x;
    if (g >= BB * IMG) return;
    int sel = blockIdx.y;
    int j = g % IMG; int b = g / IMG;
    const float* w = sel == 0 ? g_w : (sel == 1 ? th_w : ph_w);
    const float* bi = sel == 0 ? g_b : (sel == 1 ? th_b : ph_b);
    float* outp = sel == 0 ? b1p : (sel == 1 ? b2p : b3p);
    const float* ip = rr3 + (size_t)b * 64 * IMG + j;
    float vals[64];
    #pragma unroll
    for (int ci = 0; ci < 64; ++ci) vals[ci] = ip[(size_t)ci * IMG];
    int y = j / PP, xq = j % PP;
    size_t obase = ((size_t)(b * CATT) * PADW + y + 3) * PADW + (xq + 3);
    #pragma unroll
    for (int co = 0; co < CATT; ++co) {
        const float* wr = w + co * 64;
        float acc = bi[co];
        #pragma unroll
        for (int ci = 0; ci < 64; ++ci) acc += vals[ci] * wr[ci];
        outp[obase + (size_t)co * PADW * PADW] = acc;
    }
}

// ---------------- scores v4: LDS q broadcast, 2 px/thread, 14-p groups
// grid: (64*5, 6), block 128
__global__ __launch_bounds__(128) void k_scores(
    const float* __restrict__ b1p, const float* __restrict__ b3p,
    float* __restrict__ scores)
{
    __shared__ float qs[KK2][16];
    int b = blockIdx.x / 5, chunk = blockIdx.x % 5;
    int p0 = blockIdx.y * 14;
    int tid = threadIdx.x;

    int pixA = chunk * 128 + tid;
    int validA = pixA < 545;
    int validB = pixA < 544;
    int pixB = validB ? pixA + 545 : pixA;
    int yA = pixA < IMG ? pixA / PP : 0, xA = pixA < IMG ? pixA % PP : 0;
    int yB = pixB / PP, xB = pixB % PP;

    float accA[14], accB[14];
    #pragma unroll
    for (int i = 0; i < 14; ++i) { accA[i] = 0.f; accB[i] = 0.f; }

    for (int c = 0; c < CATT; ++c) {
        __syncthreads();
        for (int idx = tid; idx < KK2 * 14; idx += 128) {
            int k = idx / 14, pp = idx % 14;
            int p = p0 + pp;
            float v = 0.f;
            if (p < NPATCH) {
                int py = p / NP1, px = p % NP1;
                int row = 4 * py + k / KK, col = 4 * px + k % KK;
                v = b1p[((size_t)(b * CATT + c) * PADW + row) * PADW + col];
            }
            qs[k][pp] = v;
        }
        __syncthreads();
        const float* plane = b3p + (size_t)(b * CATT + c) * PIMG;
        #pragma unroll
        for (int ky = 0; ky < KK; ++ky) {
            const float* bA = plane + (yA + ky) * PADW + xA;
            const float* bBp = plane + (yB + ky) * PADW + xB;
            float rA[KK], rB[KK];
            #pragma unroll
            for (int i = 0; i < KK; ++i) { rA[i] = bA[i]; rB[i] = bBp[i]; }
            #pragma unroll
            for (int kx = 0; kx < KK; ++kx) {
                int k = ky * KK + kx;
                const float4* q4 = (const float4*)(&qs[k][0]);
                float4 q0 = q4[0], q1 = q4[1], q2 = q4[2];
                float2 qD = *(const float2*)(&qs[k][12]);
                float a = rA[kx], b2 = rB[kx];
                accA[0] += q0.x * a;  accB[0] += q0.x * b2;
                accA[1] += q0.y * a;  accB[1] += q0.y * b2;
                accA[2] += q0.z * a;  accB[2] += q0.z * b2;
                accA[3] += q0.w * a;  accB[3] += q0.w * b2;
                accA[4] += q1.x * a;  accB[4] += q1.x * b2;
                accA[5] += q1.y * a;  accB[5] += q1.y * b2;
                accA[6] += q1.z * a;  accB[6] += q1.z * b2;
                accA[7] += q1.w * a;  accB[7] += q1.w * b2;
                accA[8] += q2.x * a;  accB[8] += q2.x * b2;
                accA[9] += q2.y * a;  accB[9] += q2.y * b2;
                accA[10] += q2.z * a; accB[10] += q2.z * b2;
                accA[11] += q2.w * a; accB[11] += q2.w * b2;
                accA[12] += qD.x * a; accB[12] += qD.x * b2;
                accA[13] += qD.y * a; accB[13] += qD.y * b2;
            }
        }
    }
    #pragma unroll
    for (int pp = 0; pp < 14; ++pp) {
        int p = p0 + pp;
        if (p >= NPATCH) break;
        size_t rowb = (size_t)(b * NPATCH + p) * IMG;
        if (validA) scores[rowb + pixA] = accA[pp];
        if (validB) scores[rowb + pixA + 545] = accB[pp];
    }
}

// ---------------- row softmax over 1089 (in-place), scale 10
__global__ __launch_bounds__(256) void k_softmax(float* __restrict__ sc)
{
    int row = blockIdx.x;
    float* p = sc + (size_t)row * IMG;
    __shared__ float red[256];
    int tid = threadIdx.x;
    float v[5];
    float m = -1e30f;
    #pragma unroll
    for (int i = 0; i < 5; ++i) {
        int idx = tid + i * 256;
        v[i] = (idx < IMG) ? p[idx] : -1e30f;
        m = fmaxf(m, v[i]);
    }
    red[tid] = m; __syncthreads();
    for (int s = 128; s > 0; s >>= 1) { if (tid < s) red[tid] = fmaxf(red[tid], red[tid + s]); __syncthreads(); }
    m = red[0]; __syncthreads();
    float sum = 0.f;
    #pragma unroll
    for (int i = 0; i < 5; ++i) {
        int idx = tid + i * 256;
        float e = (idx < IMG) ? __expf(10.f * (v[i] - m)) : 0.f;
        v[i] = e; sum += e;
    }
    red[tid] = sum; __syncthreads();
    for (int s = 128; s > 0; s >>= 1) { if (tid < s) red[tid] += red[tid + s]; __syncthreads(); }
    float inv = 1.f / red[0];
    #pragma unroll
    for (int i = 0; i < 5; ++i) {
        int idx = tid + i * 256;
        if (idx < IMG) p[idx] = v[i] * inv;
    }
}

// ---------------- agg v4: atomic-free, 9 p-groups, wave-uniform attn reads
__global__ __launch_bounds__(256) void k_agg(
    const float* __restrict__ attn, const float* __restrict__ b2p,
    float* __restrict__ agg)
{
    int b = blockIdx.x;
    int c = blockIdx.y * 4 + (threadIdx.x >> 6);
    int k = threadIdx.x & 63;
    int p0 = blockIdx.z * 9;
    if (k >= KK2) return;
    int oy = k / KK, ox = k % KK;
    const float* vp = b2p + ((size_t)(b * CATT + c) * PADW + oy) * PADW + ox;
    const float* ap = attn + (size_t)(b * NPATCH + p0) * IMG;
    float acc[9];
    #pragma unroll
    for (int p = 0; p < 9; ++p) acc[p] = 0.f;
    for (int y = 0; y < PP; ++y) {
        const float* ar = ap + y * PP;
        const float* vr = vp + y * PADW;
        #pragma unroll 1
        for (int x = 0; x < 32; x += 4) {
            float v0 = vr[x], v1 = vr[x + 1], v2 = vr[x + 2], v3 = vr[x + 3];
            #pragma unroll
            for (int p = 0; p < 9; ++p) {
                const float* a = ar + (size_t)p * IMG + x;
                acc[p] += a[0] * v0 + a[1] * v1 + a[2] * v2 + a[3] * v3;
            }
        }
        {
            float v0 = vr[32];
            #pragma unroll
            for (int p = 0; p < 9; ++p) acc[p] += ar[(size_t)p * IMG + 32] * v0;
        }
    }
    #pragma unroll
    for (int p = 0; p < 9; ++p)
        agg[(size_t)((b * NPATCH + p0 + p) * CATT + c) * KK2 + k] = acc[p];
}

// ---------------- fold + count normalize + crop -> y_att[b,c,33,33]
__global__ __launch_bounds__(256) void k_fold(
    const float* __restrict__ agg, float* __restrict__ y_att, int total)
{
    int g = blockIdx.x * 256 + threadIdx.x;
    if (g >= total) return;
    int j = g % IMG; int t = g / IMG; int c = t % CATT; int b = t / CATT;
    int y = j / PP, x = j % PP;
    int yp = y + 3, xp = x + 3;
    int pylo = (yp - 3) >> 2; int pyhi = min(8, yp >> 2);
    int pxlo = (xp - 3) >> 2; int pxhi = min(8, xp >> 2);
    float sum = 0.f;
    int cnt = (pyhi - pylo + 1) * (pxhi - pxlo + 1);
    for (int py = pylo; py <= pyhi; ++py) {
        int ky = yp - 4 * py;
        for (int px = pxlo; px <= pxhi; ++px) {
            int kx = xp - 4 * px;
            sum += agg[(size_t)((b * NPATCH + py * NP1 + px) * CATT + c) * KK2 + ky * KK + kx];
        }
    }
    y_att[(size_t)(b * CATT + c) * IMG + j] = sum / (float)cnt;
}

// ---------------- 1x1 conv generic (W: 16->64, +bias, +rr3 residual)
__global__ __launch_bounds__(256) void k_conv1x1(
    const float* __restrict__ in, const float* __restrict__ w,
    const float* __restrict__ bias, const float* __restrict__ add,
    float* __restrict__ out, int Cin, int Cout, int total)
{
    int g = blockIdx.x * 256 + threadIdx.x;
    if (g >= total) return;
    int j = g % IMG; int t = g / IMG; int co = t % Cout; int b = t / Cout;
    const float* ip = in + (size_t)b * Cin * IMG + j;
    const float* wr = w + co * Cin;
    float acc = bias ? bias[co] : 0.f;
    #pragma unroll 4
    for (int ci = 0; ci < Cin; ++ci) acc += ip[(size_t)ci * IMG] * wr[ci];
    if (add) acc += add[g];
    out[g] = acc;
}

extern "C" void kernel_launch(void* const* d_in, const int* in_sizes, int n_in,
                              void* d_out, int out_size, void* d_ws, size_t ws_size,
                              hipStream_t stream)
{
    (void)in_sizes; (void)n_in; (void)out_size; (void)ws_size;
    const float* x      = (const float*)d_in[0];
    const float* PhiTb  = (const float*)d_in[1];
    const float* v_in   = (const float*)d_in[2];
    const float* r_in   = (const float*)d_in[3];
    const float* ru     = (const float*)d_in[4];
    const float* xx_in  = (const float*)d_in[5];
    const float* uu_in  = (const float*)d_in[6];
    const float* Phix   = (const float*)d_in[7];
    const float* PhiW   = (const float*)d_in[8];
    const float* PhiTW  = (const float*)d_in[9];
    const float* ls_p   = (const float*)d_in[10];
    const float* ls2_p  = (const float*)d_in[11];
    const float* thr_p  = (const float*)d_in[12];
    const float* beta_p = (const float*)d_in[13];
    const float* mu_p   = (const float*)d_in[14];
    const float* theta_p= (const float*)d_in[15];
    const float* conv1_w  = (const float*)d_in[16];
    const float* conv2_w  = (const float*)d_in[17];
    const float* convG1_w = (const float*)d_in[18];
    const float* convD_w  = (const float*)d_in[19];
    const float* conv1f_w = (const float*)d_in[20];
    const float* conv2f_w = (const float*)d_in[21];
    const float* conv1b_w = (const float*)d_in[22];
    const float* conv2b_w = (const float*)d_in[23];
    const float* convG_w  = (const float*)d_in[24];
    const float* convG2_w = (const float*)d_in[25];
    const float* head_w = (const float*)d_in[26];
    const float* head_b = (const float*)d_in[27];
    const float* tail_w = (const float*)d_in[28];
    const float* tail_b = (const float*)d_in[29];
    const float* rb1_w1 = (const float*)d_in[30];
    const float* rb1_b1 = (const float*)d_in[31];
    const float* rb1_w2 = (const float*)d_in[32];
    const float* rb1_b2 = (const float*)d_in[33];
    const float* rb2_w1 = (const float*)d_in[34];
    const float* rb2_b1 = (const float*)d_in[35];
    const float* rb2_w2 = (const float*)d_in[36];
    const float* rb2_b2 = (const float*)d_in[37];
    const float* g_w  = (const float*)d_in[38];
    const float* g_b  = (const float*)d_in[39];
    const float* th_w = (const float*)d_in[40];
    const float* th_b = (const float*)d_in[41];
    const float* ph_w = (const float*)d_in[42];
    const float* ph_b = (const float*)d_in[43];
    const float* W_w  = (const float*)d_in[44];
    const float* W_b  = (const float*)d_in[45];
    const float* bn_g = (const float*)d_in[46];
    const float* bn_b = (const float*)d_in[47];

    const int NSM = BB * IMG;            // 69696
    float* ws = (float*)d_ws;
    float* du    = ws;
    float* Phi_x = du + NSM;             // unused (layout stability)
    float* aubru = Phi_x + BB * MM;      // unused
    float* duv   = aubru + BB * MM;
    float* wa    = duv + NSM;
    float* duvw  = wa + NSM;
    float* rr    = duvw + NSM;
    float* bn1a  = rr + NSM;
    float* rr_nl = bn1a + NSM;
    float* xp    = rr_nl + NSM;          // unused
    float* duvww = xp + NSM;             // unused
    float* rr3   = duvww + NSM;                        // B*64*IMG
    float* R7    = rr3 + (size_t)BB * 64 * IMG;
    float* buf_a = R7;
    float* buf_b = R7 + (size_t)BB * 32 * IMG;
    float* agg   = R7;                                  // reuse after bufs dead
    float* b1p   = R7 + (size_t)2 * BB * 32 * IMG;
    float* b2p   = b1p + (size_t)BB * CATT * PIMG;
    float* b3p   = b2p + (size_t)BB * CATT * PIMG;
    float* y_att = b1p;                                 // reuse
    float* scores= b3p + (size_t)BB * CATT * PIMG;      // B*81*IMG
    float* ybuf  = scores;                              // reuse
    float* PhiWT = scores + (size_t)BB * NPATCH * IMG;  // [1089][272]
    float* PhiTWT= PhiWT + (size_t)MM * IMG;            // [272][1089]

    const int tot32 = BB * 32 * PP * 3;   // strip-11 threads (Cin=1 convs)
    const int tot64 = BB * 64 * PP * 3;

    hipMemsetAsync(b1p, 0, (size_t)3 * BB * CATT * PIMG * sizeof(float), stream);

    {
        dim3 blk(32, 8);
        dim3 g1(cdiv_i(IMG, 32), cdiv_i(MM, 32));
        k_tr<<<g1, blk, 0, stream>>>(PhiW, PhiWT, MM, IMG);
        dim3 g2(cdiv_i(MM, 32), cdiv_i(IMG, 32));
        k_tr<<<g2, blk, 0, stream>>>(PhiTW, PhiTWT, IMG, MM);
    }

    k_phiduv<<<BB, 320, 0, stream>>>(x, PhiWT, Phix, ru, PhiTb, PhiTWT, v_in, conv1_w,
                                     mu_p, beta_p, ls2_p, du, duv, wa);

    dim3 gc(BB, 11);   // banded conv32 grid

    // denoiser: head (1->32) + 2 resblocks (banded LDS conv) + fused tail+duvw + fused conv2+rr
    k_conv3x3<<<cdiv_i(tot32,256),256,0,stream>>>(duv,  head_w, head_b, nullptr, nullptr, buf_a, 1, 32, 0, tot32);
    k_conv32<<<gc,256,0,stream>>>(buf_a, rb1_w1, rb1_b1, nullptr, nullptr, buf_b, 1);
    k_conv32<<<gc,256,0,stream>>>(buf_b, rb1_w2, rb1_b2, buf_a,  nullptr, buf_a, 0);
    k_conv32<<<gc,256,0,stream>>>(buf_a, rb2_w1, rb2_b1, nullptr, nullptr, buf_b, 1);
    k_conv32<<<gc,256,0,stream>>>(buf_b, rb2_w2, rb2_b2, buf_a,  nullptr, buf_a, 0);
    k_tailduvw<<<cdiv_i(NSM,256),256,0,stream>>>(buf_a, tail_w, tail_b, duv, du, v_in, beta_p, duvw, NSM);
    k_convrr<<<cdiv_i(NSM,256),256,0,stream>>>(duvw, conv2_w, r_in, x, xx_in, wa, uu_in,
                                               theta_p, ls_p, bn_g, bn_b, rr, bn1a, NSM);
    k_conv3x3<<<cdiv_i(tot64,256),256,0,stream>>>(bn1a, convG1_w, nullptr, nullptr, nullptr, rr3, 1, 64, 1, tot64);

    // attention
    {
        dim3 gb(cdiv_i(BB * IMG, 256), 3);
        k_b123<<<gb, 256, 0, stream>>>(rr3, g_w, g_b, th_w, th_b, ph_w, ph_b, b1p, b2p, b3p);
    }
    {
        dim3 gs(BB * 5, 6);
        k_scores<<<gs, 128, 0, stream>>>(b1p, b3p, scores);
    }
    k_softmax<<<BB * NPATCH, 256, 0, stream>>>(scores);
    {
        dim3 ga(BB, 4, 9);
        k_agg<<<ga, 256, 0, stream>>>(scores, b2p, agg);
    }
    k_fold<<<cdiv_i(BB*CATT*IMG,256),256,0,stream>>>(agg, y_att, BB*CATT*IMG);
    k_conv1x1<<<cdiv_i(BB*64*IMG,256),256,0,stream>>>(y_att, W_w, W_b, rr3, ybuf, 16, 64, BB*64*IMG);
    k_conv1out<<<cdiv_i(NSM,256),256,0,stream>>>(ybuf, convG2_w, rr, rr_nl, 64, NSM);

    // ISTA soft-threshold stage
    k_conv3x3<<<cdiv_i(tot32,256),256,0,stream>>>(rr_nl, convD_w,  nullptr, nullptr, nullptr, buf_a, 1, 32, 0, tot32);
    k_conv32<<<gc,256,0,stream>>>(buf_a, conv1f_w, nullptr, nullptr, nullptr, buf_b, 1);
    k_conv32<<<gc,256,0,stream>>>(buf_b, conv2f_w, nullptr, nullptr, thr_p,   buf_a, 2);
    k_conv32<<<gc,256,0,stream>>>(buf_a, conv1b_w, nullptr, nullptr, nullptr, buf_b, 1);
    k_conv32<<<gc,256,0,stream>>>(buf_b, conv2b_w, nullptr, nullptr, nullptr, buf_a, 0);
    k_conv1out<<<cdiv_i(NSM,256),256,0,stream>>>(buf_a, convG_w, rr_nl, (float*)d_out, 32, NSM);
}

// Round 10
// 1361.618 us; speedup vs baseline: 2.3344x; 1.0470x over previous
//
#include <hip/hip_runtime.h>

#define BB 64
#define PP 33
#define IMG 1089        // 33*33
#define MM 272
#define NP1 9
#define NPATCH 81
#define KK 7
#define KK2 49
#define CATT 16
#define PADW 39
#define PIMG 1521       // 39*39

static __host__ __device__ inline int cdiv_i(int a, int b) { return (a + b - 1) / b; }

// ---------------- generic 32x32 tiled transpose: in[R][C] -> out[C][R]
__global__ __launch_bounds__(256) void k_tr(
    const float* __restrict__ in, float* __restrict__ out, int R, int C)
{
    __shared__ float t[32][33];
    int c0 = blockIdx.x * 32, r0 = blockIdx.y * 32;
    int tx = threadIdx.x, ty = threadIdx.y;
    for (int i = ty; i < 32; i += 8) {
        int r = r0 + i, c = c0 + tx;
        if (r < R && c < C) t[i][tx] = in[(size_t)r * C + c];
    }
    __syncthreads();
    for (int i = ty; i < 32; i += 8) {
        int c = c0 + i, r = r0 + tx;
        if (c < C && r < R) out[(size_t)c * R + r] = t[tx][i];
    }
}

// ---------------- fused Phi forward + duv: Phi_x/aubru live in LDS only
__global__ __launch_bounds__(320) void k_phiduv(
    const float* __restrict__ x, const float* __restrict__ PhiWT,
    const float* __restrict__ Phix_in, const float* __restrict__ ru,
    const float* __restrict__ PhiTb, const float* __restrict__ PhiTWT,
    const float* __restrict__ v_in, const float* __restrict__ conv1_w,
    const float* __restrict__ mu_p, const float* __restrict__ beta_p,
    const float* __restrict__ ls2_p,
    float* __restrict__ du, float* __restrict__ duv, float* __restrict__ wa)
{
    int b = blockIdx.x, tid = threadIdx.x;
    __shared__ float xs[IMG];
    __shared__ float ps[MM], as_[MM];
    for (int i = tid; i < IMG; i += 320) xs[i] = x[b * IMG + i];
    __syncthreads();
    if (tid < MM) {
        float mu = mu_p[0];
        const float* w = PhiWT + tid;
        float acc = 0.f;
        #pragma unroll 4
        for (int j = 0; j < IMG; ++j) acc += xs[j] * w[(size_t)j * MM];
        ps[tid] = acc;
        as_[tid] = mu * (acc - Phix_in[b * MM + tid]) - ru[b * MM + tid];
    }
    __syncthreads();
    float binv = 1.f / beta_p[0];
    float ls2 = ls2_p[0];
    for (int c = tid; c < IMG; c += 320) {
        int y = c / PP, xq = c % PP;
        float dacc = 0.f;
        #pragma unroll
        for (int dy = 0; dy < 3; ++dy) {
            int yy = y + dy - 1;
            if ((unsigned)yy >= (unsigned)PP) continue;
            #pragma unroll
            for (int dx = 0; dx < 3; ++dx) {
                int xc = xq + dx - 1;
                if ((unsigned)xc >= (unsigned)PP) continue;
                dacc += xs[yy * PP + xc] * conv1_w[dy * 3 + dx];
            }
        }
        dacc = fmaxf(dacc, 0.f);
        const float* pt = PhiTWT + c;
        float s1 = 0.f, s2 = 0.f;
        #pragma unroll 4
        for (int m = 0; m < MM; ++m) {
            float t = pt[(size_t)m * IMG];
            s1 += ps[m] * t; s2 += as_[m] * t;
        }
        int o = b * IMG + c;
        du[o] = dacc;
        duv[o] = dacc - v_in[o] * binv + ls2 * (PhiTb[o] - s1);
        wa[o] = s2;
    }
}

// ---------------- 3x3 same-pad conv, 11-px x-strip per thread (Cin=1 convs)
__global__ __launch_bounds__(256) void k_conv3x3(
    const float* __restrict__ in, const float* __restrict__ w,
    const float* __restrict__ bias, const float* __restrict__ add,
    const float* __restrict__ thr_p, float* __restrict__ out,
    int Cin, int Cout, int epil, int total)
{
    int gid = blockIdx.x * 256 + threadIdx.x;
    if (gid >= total) return;
    int s = gid % 3; int t1 = gid / 3;
    int y = t1 % PP; int t2 = t1 / PP;
    int co = t2 % Cout; int b = t2 / Cout;
    int x0 = s * 11;
    float acc[11];
    #pragma unroll
    for (int k = 0; k < 11; ++k) acc[k] = 0.f;
    const float* wb = w + (size_t)co * Cin * 9;
    const float* ib = in + (size_t)b * Cin * IMG;
    for (int ci = 0; ci < Cin; ++ci) {
        const float* img = ib + ci * IMG;
        const float* wk = wb + ci * 9;
        #pragma unroll
        for (int dy = 0; dy < 3; ++dy) {
            int yy = y + dy - 1;
            if ((unsigned)yy >= (unsigned)PP) continue;
            const float* row = img + yy * PP;
            float wA = wk[dy * 3 + 0], wB = wk[dy * 3 + 1], wC = wk[dy * 3 + 2];
            float r[13];
            #pragma unroll
            for (int i = 0; i < 13; ++i) {
                int xc = x0 - 1 + i;
                r[i] = ((unsigned)xc < (unsigned)PP) ? row[xc] : 0.f;
            }
            #pragma unroll
            for (int k = 0; k < 11; ++k)
                acc[k] += r[k] * wA + r[k + 1] * wB + r[k + 2] * wC;
        }
    }
    float bs = bias ? bias[co] : 0.f;
    float thr = (epil == 2) ? thr_p[0] : 0.f;
    int obase = (b * Cout + co) * IMG + y * PP + x0;
    #pragma unroll
    for (int k = 0; k < 11; ++k) {
        float vv = acc[k] + bs;
        if (add) vv += add[obase + k];
        if (epil == 1) vv = fmaxf(vv, 0.f);
        else if (epil == 2) {
            float av = fabsf(vv) - thr;
            vv = (vv >= 0.f ? 1.f : -1.f) * fmaxf(av, 0.f);
        }
        out[obase + k] = vv;
    }
}

// ---------------- conv32: 32->32 3x3, LDS-banded. block=(b, 3-row band), 256 thr = 32co x 8slot.
__global__ __launch_bounds__(256) void k_conv32(
    const float* __restrict__ in, const float* __restrict__ w,
    const float* __restrict__ bias, const float* __restrict__ add,
    const float* __restrict__ thr_p, float* __restrict__ out, int epil)
{
    __shared__ float s[32][5][36];
    int b = blockIdx.x;
    int r0 = blockIdx.y * 3;
    for (int idx = threadIdx.x; idx < 32 * 5 * 36; idx += 256) {
        int ci = idx / 180; int rem = idx % 180; int rr = rem / 36; int cc = rem % 36;
        int row = r0 - 1 + rr; int col = cc - 1;
        float v = 0.f;
        if ((unsigned)row < (unsigned)PP && (unsigned)col < (unsigned)PP)
            v = in[((size_t)b * 32 + ci) * IMG + row * PP + col];
        s[ci][rr][cc] = v;
    }
    __syncthreads();
    int co = threadIdx.x >> 3;
    int sl = threadIdx.x & 7;
    int c0 = sl * 4;
    bool wide = (sl == 7);
    float acc[3][5];
    #pragma unroll
    for (int i = 0; i < 3; ++i)
        #pragma unroll
        for (int j = 0; j < 5; ++j) acc[i][j] = 0.f;
    const float* wb = w + (size_t)co * 32 * 9;
    for (int ci = 0; ci < 32; ++ci) {
        const float* wk = wb + ci * 9;
        float w0 = wk[0], w1 = wk[1], w2 = wk[2], w3 = wk[3], w4 = wk[4],
              w5 = wk[5], w6 = wk[6], w7 = wk[7], w8 = wk[8];
        float wr[5][8];
        #pragma unroll
        for (int rr = 0; rr < 5; ++rr) {
            float4 a = *(const float4*)&s[ci][rr][c0];
            float4 bq = *(const float4*)&s[ci][rr][c0 + 4];
            wr[rr][0] = a.x;  wr[rr][1] = a.y;  wr[rr][2] = a.z;  wr[rr][3] = a.w;
            wr[rr][4] = bq.x; wr[rr][5] = bq.y; wr[rr][6] = bq.z; wr[rr][7] = bq.w;
        }
        #pragma unroll
        for (int orow = 0; orow < 3; ++orow) {
            #pragma unroll
            for (int j = 0; j < 5; ++j) {
                if (j < 4 || wide) {
                    acc[orow][j] += wr[orow][j] * w0 + wr[orow][j + 1] * w1 + wr[orow][j + 2] * w2
                                  + wr[orow + 1][j] * w3 + wr[orow + 1][j + 1] * w4 + wr[orow + 1][j + 2] * w5
                                  + wr[orow + 2][j] * w6 + wr[orow + 2][j + 1] * w7 + wr[orow + 2][j + 2] * w8;
                }
            }
        }
    }
    float bs = bias ? bias[co] : 0.f;
    float thr = (epil == 2) ? thr_p[0] : 0.f;
    #pragma unroll
    for (int orow = 0; orow < 3; ++orow) {
        int gr = (b * 32 + co) * IMG + (r0 + orow) * PP + c0;
        #pragma unroll
        for (int j = 0; j < 5; ++j) {
            if (j < 4 || wide) {
                float vv = acc[orow][j] + bs;
                if (add) vv += add[gr + j];
                if (epil == 1) vv = fmaxf(vv, 0.f);
                else if (epil == 2) {
                    float av = fabsf(vv) - thr;
                    vv = (vv >= 0.f ? 1.f : -1.f) * fmaxf(av, 0.f);
                }
                out[gr + j] = vv;
            }
        }
    }
}

// ---------------- fused tail conv (32->1 +bias +duv) + duvw elementwise; thread = pixel
__global__ __launch_bounds__(256) void k_tailduvw(
    const float* __restrict__ in, const float* __restrict__ w,
    const float* __restrict__ tail_b, const float* __restrict__ duv,
    const float* __restrict__ du, const float* __restrict__ v_in,
    const float* __restrict__ beta_p, float* __restrict__ duvw, int total)
{
    int g = blockIdx.x * 256 + threadIdx.x;
    if (g >= total) return;
    int j = g % IMG; int b = g / IMG;
    int y = j / PP, x = j % PP;
    bool vy0 = y > 0, vy2 = y < PP - 1, vx0 = x > 0, vx2 = x < PP - 1;
    const float* ib = in + (size_t)b * 32 * IMG + j;
    float acc = 0.f;
    for (int ci = 0; ci < 32; ++ci) {
        const float* p = ib + (size_t)ci * IMG;
        const float* wk = w + ci * 9;
        float a = 0.f;
        if (vy0) {
            if (vx0) a += p[-PP - 1] * wk[0];
            a += p[-PP] * wk[1];
            if (vx2) a += p[-PP + 1] * wk[2];
        }
        if (vx0) a += p[-1] * wk[3];
        a += p[0] * wk[4];
        if (vx2) a += p[1] * wk[5];
        if (vy2) {
            if (vx0) a += p[PP - 1] * wk[6];
            a += p[PP] * wk[7];
            if (vx2) a += p[PP + 1] * wk[8];
        }
        acc += a;
    }
    float beta = beta_p[0];
    float xp = duv[g] + acc + tail_b[0];
    duvw[g] = beta * du[g] - v_in[g] - beta * xp;
}

// ---------------- fused conv2 (1->1, relu) + rr + bn1a; thread = pixel
__global__ __launch_bounds__(256) void k_convrr(
    const float* __restrict__ duvw, const float* __restrict__ conv2_w,
    const float* __restrict__ r_in, const float* __restrict__ x_in,
    const float* __restrict__ xx_in, const float* __restrict__ wa,
    const float* __restrict__ uu_in,
    const float* __restrict__ theta_p, const float* __restrict__ ls_p,
    const float* __restrict__ bn_g, const float* __restrict__ bn_b,
    float* __restrict__ rr, float* __restrict__ bn1a, int total)
{
    int g = blockIdx.x * 256 + threadIdx.x;
    if (g >= total) return;
    int j = g % IMG; int b = g / IMG;
    int y = j / PP, x = j % PP;
    bool vy0 = y > 0, vy2 = y < PP - 1, vx0 = x > 0, vx2 = x < PP - 1;
    const float* p = duvw + (size_t)b * IMG + j;
    float a = 0.f;
    if (vy0) {
        if (vx0) a += p[-PP - 1] * conv2_w[0];
        a += p[-PP] * conv2_w[1];
        if (vx2) a += p[-PP + 1] * conv2_w[2];
    }
    if (vx0) a += p[-1] * conv2_w[3];
    a += p[0] * conv2_w[4];
    if (vx2) a += p[1] * conv2_w[5];
    if (vy2) {
        if (vx0) a += p[PP - 1] * conv2_w[6];
        a += p[PP] * conv2_w[7];
        if (vx2) a += p[PP + 1] * conv2_w[8];
    }
    float duvww = fmaxf(a, 0.f);
    float theta = theta_p[0], ls = ls_p[0];
    float d = duvww - r_in[g] + theta * (x_in[g] - xx_in[g]) + wa[g];
    float uu2 = uu_in[g] - ls * d;
    float rrv = uu2 - r_in[g] / theta;
    rr[g] = rrv;
    bn1a[g] = bn_g[0] * rrv * 0.9999950000374997f + bn_b[0];
}

// ---------------- Cout=1 3x3 conv + residual add; thread = pixel (convG2, convG)
__global__ __launch_bounds__(256) void k_conv1out(
    const float* __restrict__ in, const float* __restrict__ w,
    const float* __restrict__ add, float* __restrict__ out, int Cin, int total)
{
    int g = blockIdx.x * 256 + threadIdx.x;
    if (g >= total) return;
    int j = g % IMG; int b = g / IMG;
    int y = j / PP, x = j % PP;
    bool vy0 = y > 0, vy2 = y < PP - 1, vx0 = x > 0, vx2 = x < PP - 1;
    const float* ib = in + (size_t)b * Cin * IMG + j;
    float acc = 0.f;
    for (int ci = 0; ci < Cin; ++ci) {
        const float* p = ib + (size_t)ci * IMG;
        const float* wk = w + ci * 9;
        float a = 0.f;
        if (vy0) {
            if (vx0) a += p[-PP - 1] * wk[0];
            a += p[-PP] * wk[1];
            if (vx2) a += p[-PP + 1] * wk[2];
        }
        if (vx0) a += p[-1] * wk[3];
        a += p[0] * wk[4];
        if (vx2) a += p[1] * wk[5];
        if (vy2) {
            if (vx0) a += p[PP - 1] * wk[6];
            a += p[PP] * wk[7];
            if (vx2) a += p[PP + 1] * wk[8];
        }
        acc += a;
    }
    out[g] = acc + add[g];
}

// ---------------- b123 v2: thread = (b,px), z = which head; 64 ci in regs
__global__ __launch_bounds__(256) void k_b123(
    const float* __restrict__ rr3,
    const float* __restrict__ g_w, const float* __restrict__ g_b,
    const float* __restrict__ th_w, const float* __restrict__ th_b,
    const float* __restrict__ ph_w, const float* __restrict__ ph_b,
    float* __restrict__ b1p, float* __restrict__ b2p, float* __restrict__ b3p)
{
    int g = blockIdx.x * 256 + threadIdx.x;
    if (g >= BB * IMG) return;
    int sel = blockIdx.y;
    int j = g % IMG; int b = g / IMG;
    const float* w = sel == 0 ? g_w : (sel == 1 ? th_w : ph_w);
    const float* bi = sel == 0 ? g_b : (sel == 1 ? th_b : ph_b);
    float* outp = sel == 0 ? b1p : (sel == 1 ? b2p : b3p);
    const float* ip = rr3 + (size_t)b * 64 * IMG + j;
    float vals[64];
    #pragma unroll
    for (int ci = 0; ci < 64; ++ci) vals[ci] = ip[(size_t)ci * IMG];
    int y = j / PP, xq = j % PP;
    size_t obase = ((size_t)(b * CATT) * PADW + y + 3) * PADW + (xq + 3);
    #pragma unroll
    for (int co = 0; co < CATT; ++co) {
        const float* wr = w + co * 64;
        float acc = bi[co];
        #pragma unroll
        for (int ci = 0; ci < 64; ++ci) acc += vals[ci] * wr[ci];
        outp[obase + (size_t)co * PADW * PADW] = acc;
    }
}

// ---------------- scores v4: LDS q broadcast, 2 px/thread, 14-p groups
__global__ __launch_bounds__(128) void k_scores(
    const float* __restrict__ b1p, const float* __restrict__ b3p,
    float* __restrict__ scores)
{
    __shared__ float qs[KK2][16];
    int b = blockIdx.x / 5, chunk = blockIdx.x % 5;
    int p0 = blockIdx.y * 14;
    int tid = threadIdx.x;

    int pixA = chunk * 128 + tid;
    int validA = pixA < 545;
    int validB = pixA < 544;
    int pixB = validB ? pixA + 545 : pixA;
    int yA = pixA < IMG ? pixA / PP : 0, xA = pixA < IMG ? pixA % PP : 0;
    int yB = pixB / PP, xB = pixB % PP;

    float accA[14], accB[14];
    #pragma unroll
    for (int i = 0; i < 14; ++i) { accA[i] = 0.f; accB[i] = 0.f; }

    for (int c = 0; c < CATT; ++c) {
        __syncthreads();
        for (int idx = tid; idx < KK2 * 14; idx += 128) {
            int k = idx / 14, pp = idx % 14;
            int p = p0 + pp;
            float v = 0.f;
            if (p < NPATCH) {
                int py = p / NP1, px = p % NP1;
                int row = 4 * py + k / KK, col = 4 * px + k % KK;
                v = b1p[((size_t)(b * CATT + c) * PADW + row) * PADW + col];
            }
            qs[k][pp] = v;
        }
        __syncthreads();
        const float* plane = b3p + (size_t)(b * CATT + c) * PIMG;
        #pragma unroll
        for (int ky = 0; ky < KK; ++ky) {
            const float* bA = plane + (yA + ky) * PADW + xA;
            const float* bBp = plane + (yB + ky) * PADW + xB;
            float rA[KK], rB[KK];
            #pragma unroll
            for (int i = 0; i < KK; ++i) { rA[i] = bA[i]; rB[i] = bBp[i]; }
            #pragma unroll
            for (int kx = 0; kx < KK; ++kx) {
                int k = ky * KK + kx;
                const float4* q4 = (const float4*)(&qs[k][0]);
                float4 q0 = q4[0], q1 = q4[1], q2 = q4[2];
                float2 qD = *(const float2*)(&qs[k][12]);
                float a = rA[kx], b2 = rB[kx];
                accA[0] += q0.x * a;  accB[0] += q0.x * b2;
                accA[1] += q0.y * a;  accB[1] += q0.y * b2;
                accA[2] += q0.z * a;  accB[2] += q0.z * b2;
                accA[3] += q0.w * a;  accB[3] += q0.w * b2;
                accA[4] += q1.x * a;  accB[4] += q1.x * b2;
                accA[5] += q1.y * a;  accB[5] += q1.y * b2;
                accA[6] += q1.z * a;  accB[6] += q1.z * b2;
                accA[7] += q1.w * a;  accB[7] += q1.w * b2;
                accA[8] += q2.x * a;  accB[8] += q2.x * b2;
                accA[9] += q2.y * a;  accB[9] += q2.y * b2;
                accA[10] += q2.z * a; accB[10] += q2.z * b2;
                accA[11] += q2.w * a; accB[11] += q2.w * b2;
                accA[12] += qD.x * a; accB[12] += qD.x * b2;
                accA[13] += qD.y * a; accB[13] += qD.y * b2;
            }
        }
    }
    #pragma unroll
    for (int pp = 0; pp < 14; ++pp) {
        int p = p0 + pp;
        if (p >= NPATCH) break;
        size_t rowb = (size_t)(b * NPATCH + p) * IMG;
        if (validA) scores[rowb + pixA] = accA[pp];
        if (validB) scores[rowb + pixA + 545] = accB[pp];
    }
}

// ---------------- row softmax over 1089 (in-place), scale 10
__global__ __launch_bounds__(256) void k_softmax(float* __restrict__ sc)
{
    int row = blockIdx.x;
    float* p = sc + (size_t)row * IMG;
    __shared__ float red[256];
    int tid = threadIdx.x;
    float v[5];
    float m = -1e30f;
    #pragma unroll
    for (int i = 0; i < 5; ++i) {
        int idx = tid + i * 256;
        v[i] = (idx < IMG) ? p[idx] : -1e30f;
        m = fmaxf(m, v[i]);
    }
    red[tid] = m; __syncthreads();
    for (int s = 128; s > 0; s >>= 1) { if (tid < s) red[tid] = fmaxf(red[tid], red[tid + s]); __syncthreads(); }
    m = red[0]; __syncthreads();
    float sum = 0.f;
    #pragma unroll
    for (int i = 0; i < 5; ++i) {
        int idx = tid + i * 256;
        float e = (idx < IMG) ? __expf(10.f * (v[i] - m)) : 0.f;
        v[i] = e; sum += e;
    }
    red[tid] = sum; __syncthreads();
    for (int s = 128; s > 0; s >>= 1) { if (tid < s) red[tid] += red[tid + s]; __syncthreads(); }
    float inv = 1.f / red[0];
    #pragma unroll
    for (int i = 0; i < 5; ++i) {
        int idx = tid + i * 256;
        if (idx < IMG) p[idx] = v[i] * inv;
    }
}

// ---------------- agg v5: 2 channels/thread — 9 shared attn s-loads feed 72 FMA/step.
// grid (BB, 2, 9), block 256 = 4 c-pairs x 64 lanes (49 active).
__global__ __launch_bounds__(256) void k_agg(
    const float* __restrict__ attn, const float* __restrict__ b2p,
    float* __restrict__ agg)
{
    int b = blockIdx.x;
    int c0 = blockIdx.y * 8 + (threadIdx.x >> 6) * 2;
    int k = threadIdx.x & 63;
    int p0 = blockIdx.z * 9;
    if (k >= KK2) return;
    int oy = k / KK, ox = k % KK;
    const float* vpA = b2p + ((size_t)(b * CATT + c0) * PADW + oy) * PADW + ox;
    const float* vpB = vpA + PIMG;
    const float* ap = attn + (size_t)(b * NPATCH + p0) * IMG;
    float accA[9], accB[9];
    #pragma unroll
    for (int p = 0; p < 9; ++p) { accA[p] = 0.f; accB[p] = 0.f; }
    for (int y = 0; y < PP; ++y) {
        const float* ar = ap + y * PP;
        const float* vrA = vpA + y * PADW;
        const float* vrB = vpB + y * PADW;
        #pragma unroll 1
        for (int x = 0; x < 32; x += 4) {
            float vA0 = vrA[x], vA1 = vrA[x + 1], vA2 = vrA[x + 2], vA3 = vrA[x + 3];
            float vB0 = vrB[x], vB1 = vrB[x + 1], vB2 = vrB[x + 2], vB3 = vrB[x + 3];
            #pragma unroll
            for (int p = 0; p < 9; ++p) {
                const float* a = ar + (size_t)p * IMG + x;
                float a0 = a[0], a1 = a[1], a2 = a[2], a3 = a[3];
                accA[p] += a0 * vA0 + a1 * vA1 + a2 * vA2 + a3 * vA3;
                accB[p] += a0 * vB0 + a1 * vB1 + a2 * vB2 + a3 * vB3;
            }
        }
        {   // tail x = 32
            float vA = vrA[32], vB = vrB[32];
            #pragma unroll
            for (int p = 0; p < 9; ++p) {
                float a0 = ar[(size_t)p * IMG + 32];
                accA[p] += a0 * vA;
                accB[p] += a0 * vB;
            }
        }
    }
    #pragma unroll
    for (int p = 0; p < 9; ++p) {
        size_t base = (size_t)((b * NPATCH + p0 + p) * CATT + c0) * KK2 + k;
        agg[base] = accA[p];
        agg[base + KK2] = accB[p];
    }
}

// ---------------- fused fold + 1x1 conv (16->64) + bias + rr3 residual -> ybuf
// block: 32 px x 8 co-octets; LDS ys[32][16]
__global__ __launch_bounds__(256) void k_foldW(
    const float* __restrict__ agg, const float* __restrict__ W_w,
    const float* __restrict__ W_b, const float* __restrict__ rr3,
    float* __restrict__ ybuf)
{
    __shared__ float ys[32][16];
    int b = blockIdx.x / 35, chunk = blockIdx.x % 35;
    int px0 = chunk * 32;
    // phase 1: fold 32 px x 16 c into LDS
    for (int i = threadIdx.x; i < 32 * 16; i += 256) {
        int pl = i & 31, c = i >> 5;
        int j = px0 + pl;
        if (j < IMG) {
            int y = j / PP, x = j % PP;
            int yp = y + 3, xp = x + 3;
            int pylo = (yp - 3) >> 2; int pyhi = min(8, yp >> 2);
            int pxlo = (xp - 3) >> 2; int pxhi = min(8, xp >> 2);
            float sum = 0.f;
            int cnt = (pyhi - pylo + 1) * (pxhi - pxlo + 1);
            for (int py = pylo; py <= pyhi; ++py) {
                int ky = yp - 4 * py;
                for (int px = pxlo; px <= pxhi; ++px) {
                    int kx = xp - 4 * px;
                    sum += agg[(size_t)((b * NPATCH + py * NP1 + px) * CATT + c) * KK2 + ky * KK + kx];
                }
            }
            ys[pl][c] = sum / (float)cnt;
        } else {
            ys[pl][c] = 0.f;
        }
    }
    __syncthreads();
    // phase 2: 16->64 matvec + bias + rr3 residual
    int pl = threadIdx.x & 31, oct = threadIdx.x >> 5;
    int j = px0 + pl;
    if (j >= IMG) return;
    float yv[16];
    #pragma unroll
    for (int c = 0; c < 16; ++c) yv[c] = ys[pl][c];
    #pragma unroll
    for (int c8 = 0; c8 < 8; ++c8) {
        int co = oct * 8 + c8;
        const float* wr = W_w + co * 16;
        float acc = W_b[co];
        #pragma unroll
        for (int c = 0; c < 16; ++c) acc += yv[c] * wr[c];
        size_t o = ((size_t)b * 64 + co) * IMG + j;
        ybuf[o] = acc + rr3[o];
    }
}

extern "C" void kernel_launch(void* const* d_in, const int* in_sizes, int n_in,
                              void* d_out, int out_size, void* d_ws, size_t ws_size,
                              hipStream_t stream)
{
    (void)in_sizes; (void)n_in; (void)out_size; (void)ws_size;
    const float* x      = (const float*)d_in[0];
    const float* PhiTb  = (const float*)d_in[1];
    const float* v_in   = (const float*)d_in[2];
    const float* r_in   = (const float*)d_in[3];
    const float* ru     = (const float*)d_in[4];
    const float* xx_in  = (const float*)d_in[5];
    const float* uu_in  = (const float*)d_in[6];
    const float* Phix   = (const float*)d_in[7];
    const float* PhiW   = (const float*)d_in[8];
    const float* PhiTW  = (const float*)d_in[9];
    const float* ls_p   = (const float*)d_in[10];
    const float* ls2_p  = (const float*)d_in[11];
    const float* thr_p  = (const float*)d_in[12];
    const float* beta_p = (const float*)d_in[13];
    const float* mu_p   = (const float*)d_in[14];
    const float* theta_p= (const float*)d_in[15];
    const float* conv1_w  = (const float*)d_in[16];
    const float* conv2_w  = (const float*)d_in[17];
    const float* convG1_w = (const float*)d_in[18];
    const float* convD_w  = (const float*)d_in[19];
    const float* conv1f_w = (const float*)d_in[20];
    const float* conv2f_w = (const float*)d_in[21];
    const float* conv1b_w = (const float*)d_in[22];
    const float* conv2b_w = (const float*)d_in[23];
    const float* convG_w  = (const float*)d_in[24];
    const float* convG2_w = (const float*)d_in[25];
    const float* head_w = (const float*)d_in[26];
    const float* head_b = (const float*)d_in[27];
    const float* tail_w = (const float*)d_in[28];
    const float* tail_b = (const float*)d_in[29];
    const float* rb1_w1 = (const float*)d_in[30];
    const float* rb1_b1 = (const float*)d_in[31];
    const float* rb1_w2 = (const float*)d_in[32];
    const float* rb1_b2 = (const float*)d_in[33];
    const float* rb2_w1 = (const float*)d_in[34];
    const float* rb2_b1 = (const float*)d_in[35];
    const float* rb2_w2 = (const float*)d_in[36];
    const float* rb2_b2 = (const float*)d_in[37];
    const float* g_w  = (const float*)d_in[38];
    const float* g_b  = (const float*)d_in[39];
    const float* th_w = (const float*)d_in[40];
    const float* th_b = (const float*)d_in[41];
    const float* ph_w = (const float*)d_in[42];
    const float* ph_b = (const float*)d_in[43];
    const float* W_w  = (const float*)d_in[44];
    const float* W_b  = (const float*)d_in[45];
    const float* bn_g = (const float*)d_in[46];
    const float* bn_b = (const float*)d_in[47];

    const int NSM = BB * IMG;            // 69696
    float* ws = (float*)d_ws;
    float* du    = ws;
    float* Phi_x = du + NSM;             // unused (layout stability)
    float* aubru = Phi_x + BB * MM;      // unused
    float* duv   = aubru + BB * MM;
    float* wa    = duv + NSM;
    float* duvw  = wa + NSM;
    float* rr    = duvw + NSM;
    float* bn1a  = rr + NSM;
    float* rr_nl = bn1a + NSM;
    float* xp    = rr_nl + NSM;          // unused
    float* duvww = xp + NSM;             // unused
    float* rr3   = duvww + NSM;                        // B*64*IMG
    float* R7    = rr3 + (size_t)BB * 64 * IMG;
    float* buf_a = R7;
    float* buf_b = R7 + (size_t)BB * 32 * IMG;
    float* agg   = R7;                                  // reuse after bufs dead
    float* b1p   = R7 + (size_t)2 * BB * 32 * IMG;
    float* b2p   = b1p + (size_t)BB * CATT * PIMG;
    float* b3p   = b2p + (size_t)BB * CATT * PIMG;
    float* scores= b3p + (size_t)BB * CATT * PIMG;      // B*81*IMG
    float* ybuf  = scores;                              // reuse (attn dead after k_agg)
    float* PhiWT = scores + (size_t)BB * NPATCH * IMG;  // [1089][272]
    float* PhiTWT= PhiWT + (size_t)MM * IMG;            // [272][1089]

    const int tot32 = BB * 32 * PP * 3;   // strip-11 threads (Cin=1 convs)
    const int tot64 = BB * 64 * PP * 3;

    hipMemsetAsync(b1p, 0, (size_t)3 * BB * CATT * PIMG * sizeof(float), stream);

    {
        dim3 blk(32, 8);
        dim3 g1(cdiv_i(IMG, 32), cdiv_i(MM, 32));
        k_tr<<<g1, blk, 0, stream>>>(PhiW, PhiWT, MM, IMG);
        dim3 g2(cdiv_i(MM, 32), cdiv_i(IMG, 32));
        k_tr<<<g2, blk, 0, stream>>>(PhiTW, PhiTWT, IMG, MM);
    }

    k_phiduv<<<BB, 320, 0, stream>>>(x, PhiWT, Phix, ru, PhiTb, PhiTWT, v_in, conv1_w,
                                     mu_p, beta_p, ls2_p, du, duv, wa);

    dim3 gc(BB, 11);   // banded conv32 grid

    // denoiser
    k_conv3x3<<<cdiv_i(tot32,256),256,0,stream>>>(duv,  head_w, head_b, nullptr, nullptr, buf_a, 1, 32, 0, tot32);
    k_conv32<<<gc,256,0,stream>>>(buf_a, rb1_w1, rb1_b1, nullptr, nullptr, buf_b, 1);
    k_conv32<<<gc,256,0,stream>>>(buf_b, rb1_w2, rb1_b2, buf_a,  nullptr, buf_a, 0);
    k_conv32<<<gc,256,0,stream>>>(buf_a, rb2_w1, rb2_b1, nullptr, nullptr, buf_b, 1);
    k_conv32<<<gc,256,0,stream>>>(buf_b, rb2_w2, rb2_b2, buf_a,  nullptr, buf_a, 0);
    k_tailduvw<<<cdiv_i(NSM,256),256,0,stream>>>(buf_a, tail_w, tail_b, duv, du, v_in, beta_p, duvw, NSM);
    k_convrr<<<cdiv_i(NSM,256),256,0,stream>>>(duvw, conv2_w, r_in, x, xx_in, wa, uu_in,
                                               theta_p, ls_p, bn_g, bn_b, rr, bn1a, NSM);
    k_conv3x3<<<cdiv_i(tot64,256),256,0,stream>>>(bn1a, convG1_w, nullptr, nullptr, nullptr, rr3, 1, 64, 1, tot64);

    // attention
    {
        dim3 gb(cdiv_i(BB * IMG, 256), 3);
        k_b123<<<gb, 256, 0, stream>>>(rr3, g_w, g_b, th_w, th_b, ph_w, ph_b, b1p, b2p, b3p);
    }
    {
        dim3 gs(BB * 5, 6);
        k_scores<<<gs, 128, 0, stream>>>(b1p, b3p, scores);
    }
    k_softmax<<<BB * NPATCH, 256, 0, stream>>>(scores);
    {
        dim3 ga(BB, 2, 9);
        k_agg<<<ga, 256, 0, stream>>>(scores, b2p, agg);
    }
    k_foldW<<<BB * 35, 256, 0, stream>>>(agg, W_w, W_b, rr3, ybuf);
    k_conv1out<<<cdiv_i(NSM,256),256,0,stream>>>(ybuf, convG2_w, rr, rr_nl, 64, NSM);

    // ISTA soft-threshold stage
    k_conv3x3<<<cdiv_i(tot32,256),256,0,stream>>>(rr_nl, convD_w,  nullptr, nullptr, nullptr, buf_a, 1, 32, 0, tot32);
    k_conv32<<<gc,256,0,stream>>>(buf_a, conv1f_w, nullptr, nullptr, nullptr, buf_b, 1);
    k_conv32<<<gc,256,0,stream>>>(buf_b, conv2f_w, nullptr, nullptr, thr_p,   buf_a, 2);
    k_conv32<<<gc,256,0,stream>>>(buf_a, conv1b_w, nullptr, nullptr, nullptr, buf_b, 1);
    k_conv32<<<gc,256,0,stream>>>(buf_b, conv2b_w, nullptr, nullptr, nullptr, buf_a, 0);
    k_conv1out<<<cdiv_i(NSM,256),256,0,stream>>>(buf_a, convG_w, rr_nl, (float*)d_out, 32, NSM);
}

// Round 11
// 1047.619 us; speedup vs baseline: 3.0340x; 1.2997x over previous
//
#include <hip/hip_runtime.h>

#define BB 64
#define PP 33
#define IMG 1089        // 33*33
#define MM 272
#define NP1 9
#define NPATCH 81
#define KK 7
#define KK2 49
#define CATT 16
#define PADW 39
#define PIMG 1521       // 39*39

static __host__ __device__ inline int cdiv_i(int a, int b) { return (a + b - 1) / b; }

// ---------------- generic 32x32 tiled transpose: in[R][C] -> out[C][R]
__global__ __launch_bounds__(256) void k_tr(
    const float* __restrict__ in, float* __restrict__ out, int R, int C)
{
    __shared__ float t[32][33];
    int c0 = blockIdx.x * 32, r0 = blockIdx.y * 32;
    int tx = threadIdx.x, ty = threadIdx.y;
    for (int i = ty; i < 32; i += 8) {
        int r = r0 + i, c = c0 + tx;
        if (r < R && c < C) t[i][tx] = in[(size_t)r * C + c];
    }
    __syncthreads();
    for (int i = ty; i < 32; i += 8) {
        int c = c0 + i, r = r0 + tx;
        if (c < C && r < R) out[(size_t)c * R + r] = t[tx][i];
    }
}

// ---------------- phi v2: wave-per-m, coalesced x/PhiW reads, shuffle reduce
// grid (BB, 68), block 256 = 4 waves = 4 m values
__global__ __launch_bounds__(256) void k_phi2(
    const float* __restrict__ x, const float* __restrict__ PhiW,
    const float* __restrict__ Phix_in, const float* __restrict__ ru,
    const float* __restrict__ mu_p,
    float* __restrict__ Phi_x, float* __restrict__ aubru)
{
    int b = blockIdx.x;
    int m = blockIdx.y * 4 + (threadIdx.x >> 6);
    int lane = threadIdx.x & 63;
    const float* xb = x + (size_t)b * IMG;
    const float* w = PhiW + (size_t)m * IMG;
    float acc = 0.f;
    for (int j = lane; j < IMG; j += 64) acc += xb[j] * w[j];
    #pragma unroll
    for (int off = 32; off; off >>= 1) acc += __shfl_down(acc, off);
    if (lane == 0) {
        float mu = mu_p[0];
        Phi_x[b * MM + m] = acc;
        aubru[b * MM + m] = mu * (acc - Phix_in[b * MM + m]) - ru[b * MM + m];
    }
}

// ---------------- duv v2: block = 64 px x 4 m-quarters (68 m each), LDS reduce
// grid (18, BB) = 1152 blocks
__global__ __launch_bounds__(256) void k_duv2(
    const float* __restrict__ x, const float* __restrict__ v_in,
    const float* __restrict__ PhiTb, const float* __restrict__ PhiTWT,
    const float* __restrict__ Phi_x, const float* __restrict__ aubru,
    const float* __restrict__ conv1_w,
    const float* __restrict__ beta_p, const float* __restrict__ ls2_p,
    float* __restrict__ du, float* __restrict__ duv, float* __restrict__ wa)
{
    __shared__ float ps[MM], as_[MM];
    __shared__ float red[2][64][4];
    int b = blockIdx.y;
    int c0 = blockIdx.x * 64;
    int tid = threadIdx.x;
    for (int i = tid; i < MM; i += 256) { ps[i] = Phi_x[b * MM + i]; as_[i] = aubru[b * MM + i]; }
    __syncthreads();
    int pl = tid & 63, q = tid >> 6;
    int c = c0 + pl;
    bool act = c < IMG;
    int cc = act ? c : 0;
    float s1 = 0.f, s2 = 0.f;
    const float* pt = PhiTWT + cc;
    int m0 = q * 68;
    #pragma unroll 4
    for (int m = m0; m < m0 + 68; ++m) {
        float t = pt[(size_t)m * IMG];
        s1 += ps[m] * t; s2 += as_[m] * t;
    }
    red[0][pl][q] = s1; red[1][pl][q] = s2;
    __syncthreads();
    if (q == 0 && act) {
        s1 = red[0][pl][0] + red[0][pl][1] + red[0][pl][2] + red[0][pl][3];
        s2 = red[1][pl][0] + red[1][pl][1] + red[1][pl][2] + red[1][pl][3];
        int y = c / PP, xq = c % PP;
        const float* xb = x + (size_t)b * IMG;
        float dacc = 0.f;
        #pragma unroll
        for (int dy = 0; dy < 3; ++dy) {
            int yy = y + dy - 1;
            if ((unsigned)yy >= (unsigned)PP) continue;
            #pragma unroll
            for (int dx = 0; dx < 3; ++dx) {
                int xc = xq + dx - 1;
                if ((unsigned)xc >= (unsigned)PP) continue;
                dacc += xb[yy * PP + xc] * conv1_w[dy * 3 + dx];
            }
        }
        dacc = fmaxf(dacc, 0.f);
        float binv = 1.f / beta_p[0];
        float ls2 = ls2_p[0];
        int o = b * IMG + c;
        du[o] = dacc;
        duv[o] = dacc - v_in[o] * binv + ls2 * (PhiTb[o] - s1);
        wa[o] = s2;
    }
}

// ---------------- 3x3 same-pad conv, 11-px x-strip per thread (Cin=1 convs)
__global__ __launch_bounds__(256) void k_conv3x3(
    const float* __restrict__ in, const float* __restrict__ w,
    const float* __restrict__ bias, const float* __restrict__ add,
    const float* __restrict__ thr_p, float* __restrict__ out,
    int Cin, int Cout, int epil, int total)
{
    int gid = blockIdx.x * 256 + threadIdx.x;
    if (gid >= total) return;
    int s = gid % 3; int t1 = gid / 3;
    int y = t1 % PP; int t2 = t1 / PP;
    int co = t2 % Cout; int b = t2 / Cout;
    int x0 = s * 11;
    float acc[11];
    #pragma unroll
    for (int k = 0; k < 11; ++k) acc[k] = 0.f;
    const float* wb = w + (size_t)co * Cin * 9;
    const float* ib = in + (size_t)b * Cin * IMG;
    for (int ci = 0; ci < Cin; ++ci) {
        const float* img = ib + ci * IMG;
        const float* wk = wb + ci * 9;
        #pragma unroll
        for (int dy = 0; dy < 3; ++dy) {
            int yy = y + dy - 1;
            if ((unsigned)yy >= (unsigned)PP) continue;
            const float* row = img + yy * PP;
            float wA = wk[dy * 3 + 0], wB = wk[dy * 3 + 1], wC = wk[dy * 3 + 2];
            float r[13];
            #pragma unroll
            for (int i = 0; i < 13; ++i) {
                int xc = x0 - 1 + i;
                r[i] = ((unsigned)xc < (unsigned)PP) ? row[xc] : 0.f;
            }
            #pragma unroll
            for (int k = 0; k < 11; ++k)
                acc[k] += r[k] * wA + r[k + 1] * wB + r[k + 2] * wC;
        }
    }
    float bs = bias ? bias[co] : 0.f;
    float thr = (epil == 2) ? thr_p[0] : 0.f;
    int obase = (b * Cout + co) * IMG + y * PP + x0;
    #pragma unroll
    for (int k = 0; k < 11; ++k) {
        float vv = acc[k] + bs;
        if (add) vv += add[obase + k];
        if (epil == 1) vv = fmaxf(vv, 0.f);
        else if (epil == 2) {
            float av = fabsf(vv) - thr;
            vv = (vv >= 0.f ? 1.f : -1.f) * fmaxf(av, 0.f);
        }
        out[obase + k] = vv;
    }
}

// ---------------- conv32: 32->32 3x3, LDS-banded. block=(b, 3-row band), 256 thr = 32co x 8slot.
__global__ __launch_bounds__(256) void k_conv32(
    const float* __restrict__ in, const float* __restrict__ w,
    const float* __restrict__ bias, const float* __restrict__ add,
    const float* __restrict__ thr_p, float* __restrict__ out, int epil)
{
    __shared__ float s[32][5][36];
    int b = blockIdx.x;
    int r0 = blockIdx.y * 3;
    for (int idx = threadIdx.x; idx < 32 * 5 * 36; idx += 256) {
        int ci = idx / 180; int rem = idx % 180; int rr = rem / 36; int cc = rem % 36;
        int row = r0 - 1 + rr; int col = cc - 1;
        float v = 0.f;
        if ((unsigned)row < (unsigned)PP && (unsigned)col < (unsigned)PP)
            v = in[((size_t)b * 32 + ci) * IMG + row * PP + col];
        s[ci][rr][cc] = v;
    }
    __syncthreads();
    int co = threadIdx.x >> 3;
    int sl = threadIdx.x & 7;
    int c0 = sl * 4;
    bool wide = (sl == 7);
    float acc[3][5];
    #pragma unroll
    for (int i = 0; i < 3; ++i)
        #pragma unroll
        for (int j = 0; j < 5; ++j) acc[i][j] = 0.f;
    const float* wb = w + (size_t)co * 32 * 9;
    for (int ci = 0; ci < 32; ++ci) {
        const float* wk = wb + ci * 9;
        float w0 = wk[0], w1 = wk[1], w2 = wk[2], w3 = wk[3], w4 = wk[4],
              w5 = wk[5], w6 = wk[6], w7 = wk[7], w8 = wk[8];
        float wr[5][8];
        #pragma unroll
        for (int rr = 0; rr < 5; ++rr) {
            float4 a = *(const float4*)&s[ci][rr][c0];
            float4 bq = *(const float4*)&s[ci][rr][c0 + 4];
            wr[rr][0] = a.x;  wr[rr][1] = a.y;  wr[rr][2] = a.z;  wr[rr][3] = a.w;
            wr[rr][4] = bq.x; wr[rr][5] = bq.y; wr[rr][6] = bq.z; wr[rr][7] = bq.w;
        }
        #pragma unroll
        for (int orow = 0; orow < 3; ++orow) {
            #pragma unroll
            for (int j = 0; j < 5; ++j) {
                if (j < 4 || wide) {
                    acc[orow][j] += wr[orow][j] * w0 + wr[orow][j + 1] * w1 + wr[orow][j + 2] * w2
                                  + wr[orow + 1][j] * w3 + wr[orow + 1][j + 1] * w4 + wr[orow + 1][j + 2] * w5
                                  + wr[orow + 2][j] * w6 + wr[orow + 2][j + 1] * w7 + wr[orow + 2][j + 2] * w8;
                }
            }
        }
    }
    float bs = bias ? bias[co] : 0.f;
    float thr = (epil == 2) ? thr_p[0] : 0.f;
    #pragma unroll
    for (int orow = 0; orow < 3; ++orow) {
        int gr = (b * 32 + co) * IMG + (r0 + orow) * PP + c0;
        #pragma unroll
        for (int j = 0; j < 5; ++j) {
            if (j < 4 || wide) {
                float vv = acc[orow][j] + bs;
                if (add) vv += add[gr + j];
                if (epil == 1) vv = fmaxf(vv, 0.f);
                else if (epil == 2) {
                    float av = fabsf(vv) - thr;
                    vv = (vv >= 0.f ? 1.f : -1.f) * fmaxf(av, 0.f);
                }
                out[gr + j] = vv;
            }
        }
    }
}

// ---------------- tailduvw v2: 64 px x 4 ci-octs, LDS reduce; grid cdiv(NSM,64)
__global__ __launch_bounds__(256) void k_tailduvw(
    const float* __restrict__ in, const float* __restrict__ w,
    const float* __restrict__ tail_b, const float* __restrict__ duv,
    const float* __restrict__ du, const float* __restrict__ v_in,
    const float* __restrict__ beta_p, float* __restrict__ duvw, int total)
{
    __shared__ float red[64][4];
    int g0 = blockIdx.x * 64;
    int pl = threadIdx.x & 63, q = threadIdx.x >> 6;
    int g = g0 + pl;
    bool act = g < total;
    int gg = act ? g : 0;
    int j = gg % IMG; int b = gg / IMG;
    int y = j / PP, x = j % PP;
    bool vy0 = y > 0, vy2 = y < PP - 1, vx0 = x > 0, vx2 = x < PP - 1;
    const float* ib = in + ((size_t)b * 32 + q * 8) * IMG + j;
    float acc = 0.f;
    #pragma unroll
    for (int ci = 0; ci < 8; ++ci) {
        const float* p = ib + (size_t)ci * IMG;
        const float* wk = w + (q * 8 + ci) * 9;
        float a = 0.f;
        if (vy0) {
            if (vx0) a += p[-PP - 1] * wk[0];
            a += p[-PP] * wk[1];
            if (vx2) a += p[-PP + 1] * wk[2];
        }
        if (vx0) a += p[-1] * wk[3];
        a += p[0] * wk[4];
        if (vx2) a += p[1] * wk[5];
        if (vy2) {
            if (vx0) a += p[PP - 1] * wk[6];
            a += p[PP] * wk[7];
            if (vx2) a += p[PP + 1] * wk[8];
        }
        acc += a;
    }
    red[pl][q] = acc;
    __syncthreads();
    if (q == 0 && act) {
        float conv = red[pl][0] + red[pl][1] + red[pl][2] + red[pl][3];
        float beta = beta_p[0];
        float xp = duv[g] + conv + tail_b[0];
        duvw[g] = beta * du[g] - v_in[g] - beta * xp;
    }
}

// ---------------- fused conv2 (1->1, relu) + rr + bn1a; thread = pixel
__global__ __launch_bounds__(256) void k_convrr(
    const float* __restrict__ duvw, const float* __restrict__ conv2_w,
    const float* __restrict__ r_in, const float* __restrict__ x_in,
    const float* __restrict__ xx_in, const float* __restrict__ wa,
    const float* __restrict__ uu_in,
    const float* __restrict__ theta_p, const float* __restrict__ ls_p,
    const float* __restrict__ bn_g, const float* __restrict__ bn_b,
    float* __restrict__ rr, float* __restrict__ bn1a, int total)
{
    int g = blockIdx.x * 256 + threadIdx.x;
    if (g >= total) return;
    int j = g % IMG; int b = g / IMG;
    int y = j / PP, x = j % PP;
    bool vy0 = y > 0, vy2 = y < PP - 1, vx0 = x > 0, vx2 = x < PP - 1;
    const float* p = duvw + (size_t)b * IMG + j;
    float a = 0.f;
    if (vy0) {
        if (vx0) a += p[-PP - 1] * conv2_w[0];
        a += p[-PP] * conv2_w[1];
        if (vx2) a += p[-PP + 1] * conv2_w[2];
    }
    if (vx0) a += p[-1] * conv2_w[3];
    a += p[0] * conv2_w[4];
    if (vx2) a += p[1] * conv2_w[5];
    if (vy2) {
        if (vx0) a += p[PP - 1] * conv2_w[6];
        a += p[PP] * conv2_w[7];
        if (vx2) a += p[PP + 1] * conv2_w[8];
    }
    float duvww = fmaxf(a, 0.f);
    float theta = theta_p[0], ls = ls_p[0];
    float d = duvww - r_in[g] + theta * (x_in[g] - xx_in[g]) + wa[g];
    float uu2 = uu_in[g] - ls * d;
    float rrv = uu2 - r_in[g] / theta;
    rr[g] = rrv;
    bn1a[g] = bn_g[0] * rrv * 0.9999950000374997f + bn_b[0];
}

// ---------------- conv1out v2: Cout=1 conv + residual, 64 px x 4 ci-groups, LDS reduce
__global__ __launch_bounds__(256) void k_conv1out(
    const float* __restrict__ in, const float* __restrict__ w,
    const float* __restrict__ add, float* __restrict__ out, int Cin, int total)
{
    __shared__ float red[64][4];
    int g0 = blockIdx.x * 64;
    int pl = threadIdx.x & 63, q = threadIdx.x >> 6;
    int g = g0 + pl;
    bool act = g < total;
    int gg = act ? g : 0;
    int j = gg % IMG; int b = gg / IMG;
    int y = j / PP, x = j % PP;
    bool vy0 = y > 0, vy2 = y < PP - 1, vx0 = x > 0, vx2 = x < PP - 1;
    int cpq = Cin >> 2;
    const float* ib = in + ((size_t)b * Cin + q * cpq) * IMG + j;
    float acc = 0.f;
    for (int ci = 0; ci < cpq; ++ci) {
        const float* p = ib + (size_t)ci * IMG;
        const float* wk = w + (q * cpq + ci) * 9;
        float a = 0.f;
        if (vy0) {
            if (vx0) a += p[-PP - 1] * wk[0];
            a += p[-PP] * wk[1];
            if (vx2) a += p[-PP + 1] * wk[2];
        }
        if (vx0) a += p[-1] * wk[3];
        a += p[0] * wk[4];
        if (vx2) a += p[1] * wk[5];
        if (vy2) {
            if (vx0) a += p[PP - 1] * wk[6];
            a += p[PP] * wk[7];
            if (vx2) a += p[PP + 1] * wk[8];
        }
        acc += a;
    }
    red[pl][q] = acc;
    __syncthreads();
    if (q == 0 && act)
        out[g] = red[pl][0] + red[pl][1] + red[pl][2] + red[pl][3] + add[g];
}

// ---------------- b123 v2: thread = (b,px), z = which head; 64 ci in regs
__global__ __launch_bounds__(256) void k_b123(
    const float* __restrict__ rr3,
    const float* __restrict__ g_w, const float* __restrict__ g_b,
    const float* __restrict__ th_w, const float* __restrict__ th_b,
    const float* __restrict__ ph_w, const float* __restrict__ ph_b,
    float* __restrict__ b1p, float* __restrict__ b2p, float* __restrict__ b3p)
{
    int g = blockIdx.x * 256 + threadIdx.x;
    if (g >= BB * IMG) return;
    int sel = blockIdx.y;
    int j = g % IMG; int b = g / IMG;
    const float* w = sel == 0 ? g_w : (sel == 1 ? th_w : ph_w);
    const float* bi = sel == 0 ? g_b : (sel == 1 ? th_b : ph_b);
    float* outp = sel == 0 ? b1p : (sel == 1 ? b2p : b3p);
    const float* ip = rr3 + (size_t)b * 64 * IMG + j;
    float vals[64];
    #pragma unroll
    for (int ci = 0; ci < 64; ++ci) vals[ci] = ip[(size_t)ci * IMG];
    int y = j / PP, xq = j % PP;
    size_t obase = ((size_t)(b * CATT) * PADW + y + 3) * PADW + (xq + 3);
    #pragma unroll
    for (int co = 0; co < CATT; ++co) {
        const float* wr = w + co * 64;
        float acc = bi[co];
        #pragma unroll
        for (int ci = 0; ci < 64; ++ci) acc += vals[ci] * wr[ci];
        outp[obase + (size_t)co * PADW * PADW] = acc;
    }
}

// ---------------- scores v4: LDS q broadcast, 2 px/thread, 14-p groups
__global__ __launch_bounds__(128) void k_scores(
    const float* __restrict__ b1p, const float* __restrict__ b3p,
    float* __restrict__ scores)
{
    __shared__ float qs[KK2][16];
    int b = blockIdx.x / 5, chunk = blockIdx.x % 5;
    int p0 = blockIdx.y * 14;
    int tid = threadIdx.x;

    int pixA = chunk * 128 + tid;
    int validA = pixA < 545;
    int validB = pixA < 544;
    int pixB = validB ? pixA + 545 : pixA;
    int yA = pixA < IMG ? pixA / PP : 0, xA = pixA < IMG ? pixA % PP : 0;
    int yB = pixB / PP, xB = pixB % PP;

    float accA[14], accB[14];
    #pragma unroll
    for (int i = 0; i < 14; ++i) { accA[i] = 0.f; accB[i] = 0.f; }

    for (int c = 0; c < CATT; ++c) {
        __syncthreads();
        for (int idx = tid; idx < KK2 * 14; idx += 128) {
            int k = idx / 14, pp = idx % 14;
            int p = p0 + pp;
            float v = 0.f;
            if (p < NPATCH) {
                int py = p / NP1, px = p % NP1;
                int row = 4 * py + k / KK, col = 4 * px + k % KK;
                v = b1p[((size_t)(b * CATT + c) * PADW + row) * PADW + col];
            }
            qs[k][pp] = v;
        }
        __syncthreads();
        const float* plane = b3p + (size_t)(b * CATT + c) * PIMG;
        #pragma unroll
        for (int ky = 0; ky < KK; ++ky) {
            const float* bA = plane + (yA + ky) * PADW + xA;
            const float* bBp = plane + (yB + ky) * PADW + xB;
            float rA[KK], rB[KK];
            #pragma unroll
            for (int i = 0; i < KK; ++i) { rA[i] = bA[i]; rB[i] = bBp[i]; }
            #pragma unroll
            for (int kx = 0; kx < KK; ++kx) {
                int k = ky * KK + kx;
                const float4* q4 = (const float4*)(&qs[k][0]);
                float4 q0 = q4[0], q1 = q4[1], q2 = q4[2];
                float2 qD = *(const float2*)(&qs[k][12]);
                float a = rA[kx], b2 = rB[kx];
                accA[0] += q0.x * a;  accB[0] += q0.x * b2;
                accA[1] += q0.y * a;  accB[1] += q0.y * b2;
                accA[2] += q0.z * a;  accB[2] += q0.z * b2;
                accA[3] += q0.w * a;  accB[3] += q0.w * b2;
                accA[4] += q1.x * a;  accB[4] += q1.x * b2;
                accA[5] += q1.y * a;  accB[5] += q1.y * b2;
                accA[6] += q1.z * a;  accB[6] += q1.z * b2;
                accA[7] += q1.w * a;  accB[7] += q1.w * b2;
                accA[8] += q2.x * a;  accB[8] += q2.x * b2;
                accA[9] += q2.y * a;  accB[9] += q2.y * b2;
                accA[10] += q2.z * a; accB[10] += q2.z * b2;
                accA[11] += q2.w * a; accB[11] += q2.w * b2;
                accA[12] += qD.x * a; accB[12] += qD.x * b2;
                accA[13] += qD.y * a; accB[13] += qD.y * b2;
            }
        }
    }
    #pragma unroll
    for (int pp = 0; pp < 14; ++pp) {
        int p = p0 + pp;
        if (p >= NPATCH) break;
        size_t rowb = (size_t)(b * NPATCH + p) * IMG;
        if (validA) scores[rowb + pixA] = accA[pp];
        if (validB) scores[rowb + pixA + 545] = accB[pp];
    }
}

// ---------------- row softmax over 1089 (in-place), scale 10
__global__ __launch_bounds__(256) void k_softmax(float* __restrict__ sc)
{
    int row = blockIdx.x;
    float* p = sc + (size_t)row * IMG;
    __shared__ float red[256];
    int tid = threadIdx.x;
    float v[5];
    float m = -1e30f;
    #pragma unroll
    for (int i = 0; i < 5; ++i) {
        int idx = tid + i * 256;
        v[i] = (idx < IMG) ? p[idx] : -1e30f;
        m = fmaxf(m, v[i]);
    }
    red[tid] = m; __syncthreads();
    for (int s = 128; s > 0; s >>= 1) { if (tid < s) red[tid] = fmaxf(red[tid], red[tid + s]); __syncthreads(); }
    m = red[0]; __syncthreads();
    float sum = 0.f;
    #pragma unroll
    for (int i = 0; i < 5; ++i) {
        int idx = tid + i * 256;
        float e = (idx < IMG) ? __expf(10.f * (v[i] - m)) : 0.f;
        v[i] = e; sum += e;
    }
    red[tid] = sum; __syncthreads();
    for (int s = 128; s > 0; s >>= 1) { if (tid < s) red[tid] += red[tid + s]; __syncthreads(); }
    float inv = 1.f / red[0];
    #pragma unroll
    for (int i = 0; i < 5; ++i) {
        int idx = tid + i * 256;
        if (idx < IMG) p[idx] = v[i] * inv;
    }
}

// ---------------- agg v5: 2 channels/thread — 9 shared attn s-loads feed 72 FMA/step.
__global__ __launch_bounds__(256) void k_agg(
    const float* __restrict__ attn, const float* __restrict__ b2p,
    float* __restrict__ agg)
{
    int b = blockIdx.x;
    int c0 = blockIdx.y * 8 + (threadIdx.x >> 6) * 2;
    int k = threadIdx.x & 63;
    int p0 = blockIdx.z * 9;
    if (k >= KK2) return;
    int oy = k / KK, ox = k % KK;
    const float* vpA = b2p + ((size_t)(b * CATT + c0) * PADW + oy) * PADW + ox;
    const float* vpB = vpA + PIMG;
    const float* ap = attn + (size_t)(b * NPATCH + p0) * IMG;
    float accA[9], accB[9];
    #pragma unroll
    for (int p = 0; p < 9; ++p) { accA[p] = 0.f; accB[p] = 0.f; }
    for (int y = 0; y < PP; ++y) {
        const float* ar = ap + y * PP;
        const float* vrA = vpA + y * PADW;
        const float* vrB = vpB + y * PADW;
        #pragma unroll 1
        for (int x = 0; x < 32; x += 4) {
            float vA0 = vrA[x], vA1 = vrA[x + 1], vA2 = vrA[x + 2], vA3 = vrA[x + 3];
            float vB0 = vrB[x], vB1 = vrB[x + 1], vB2 = vrB[x + 2], vB3 = vrB[x + 3];
            #pragma unroll
            for (int p = 0; p < 9; ++p) {
                const float* a = ar + (size_t)p * IMG + x;
                float a0 = a[0], a1 = a[1], a2 = a[2], a3 = a[3];
                accA[p] += a0 * vA0 + a1 * vA1 + a2 * vA2 + a3 * vA3;
                accB[p] += a0 * vB0 + a1 * vB1 + a2 * vB2 + a3 * vB3;
            }
        }
        {   // tail x = 32
            float vA = vrA[32], vB = vrB[32];
            #pragma unroll
            for (int p = 0; p < 9; ++p) {
                float a0 = ar[(size_t)p * IMG + 32];
                accA[p] += a0 * vA;
                accB[p] += a0 * vB;
            }
        }
    }
    #pragma unroll
    for (int p = 0; p < 9; ++p) {
        size_t base = (size_t)((b * NPATCH + p0 + p) * CATT + c0) * KK2 + k;
        agg[base] = accA[p];
        agg[base + KK2] = accB[p];
    }
}

// ---------------- fused fold + 1x1 conv (16->64) + bias + rr3 residual -> ybuf
__global__ __launch_bounds__(256) void k_foldW(
    const float* __restrict__ agg, const float* __restrict__ W_w,
    const float* __restrict__ W_b, const float* __restrict__ rr3,
    float* __restrict__ ybuf)
{
    __shared__ float ys[32][16];
    int b = blockIdx.x / 35, chunk = blockIdx.x % 35;
    int px0 = chunk * 32;
    for (int i = threadIdx.x; i < 32 * 16; i += 256) {
        int pl = i & 31, c = i >> 5;
        int j = px0 + pl;
        if (j < IMG) {
            int y = j / PP, x = j % PP;
            int yp = y + 3, xp = x + 3;
            int pylo = (yp - 3) >> 2; int pyhi = min(8, yp >> 2);
            int pxlo = (xp - 3) >> 2; int pxhi = min(8, xp >> 2);
            float sum = 0.f;
            int cnt = (pyhi - pylo + 1) * (pxhi - pxlo + 1);
            for (int py = pylo; py <= pyhi; ++py) {
                int ky = yp - 4 * py;
                for (int px = pxlo; px <= pxhi; ++px) {
                    int kx = xp - 4 * px;
                    sum += agg[(size_t)((b * NPATCH + py * NP1 + px) * CATT + c) * KK2 + ky * KK + kx];
                }
            }
            ys[pl][c] = sum / (float)cnt;
        } else {
            ys[pl][c] = 0.f;
        }
    }
    __syncthreads();
    int pl = threadIdx.x & 31, oct = threadIdx.x >> 5;
    int j = px0 + pl;
    if (j >= IMG) return;
    float yv[16];
    #pragma unroll
    for (int c = 0; c < 16; ++c) yv[c] = ys[pl][c];
    #pragma unroll
    for (int c8 = 0; c8 < 8; ++c8) {
        int co = oct * 8 + c8;
        const float* wr = W_w + co * 16;
        float acc = W_b[co];
        #pragma unroll
        for (int c = 0; c < 16; ++c) acc += yv[c] * wr[c];
        size_t o = ((size_t)b * 64 + co) * IMG + j;
        ybuf[o] = acc + rr3[o];
    }
}

extern "C" void kernel_launch(void* const* d_in, const int* in_sizes, int n_in,
                              void* d_out, int out_size, void* d_ws, size_t ws_size,
                              hipStream_t stream)
{
    (void)in_sizes; (void)n_in; (void)out_size; (void)ws_size;
    const float* x      = (const float*)d_in[0];
    const float* PhiTb  = (const float*)d_in[1];
    const float* v_in   = (const float*)d_in[2];
    const float* r_in   = (const float*)d_in[3];
    const float* ru     = (const float*)d_in[4];
    const float* xx_in  = (const float*)d_in[5];
    const float* uu_in  = (const float*)d_in[6];
    const float* Phix   = (const float*)d_in[7];
    const float* PhiW   = (const float*)d_in[8];
    const float* PhiTW  = (const float*)d_in[9];
    const float* ls_p   = (const float*)d_in[10];
    const float* ls2_p  = (const float*)d_in[11];
    const float* thr_p  = (const float*)d_in[12];
    const float* beta_p = (const float*)d_in[13];
    const float* mu_p   = (const float*)d_in[14];
    const float* theta_p= (const float*)d_in[15];
    const float* conv1_w  = (const float*)d_in[16];
    const float* conv2_w  = (const float*)d_in[17];
    const float* convG1_w = (const float*)d_in[18];
    const float* convD_w  = (const float*)d_in[19];
    const float* conv1f_w = (const float*)d_in[20];
    const float* conv2f_w = (const float*)d_in[21];
    const float* conv1b_w = (const float*)d_in[22];
    const float* conv2b_w = (const float*)d_in[23];
    const float* convG_w  = (const float*)d_in[24];
    const float* convG2_w = (const float*)d_in[25];
    const float* head_w = (const float*)d_in[26];
    const float* head_b = (const float*)d_in[27];
    const float* tail_w = (const float*)d_in[28];
    const float* tail_b = (const float*)d_in[29];
    const float* rb1_w1 = (const float*)d_in[30];
    const float* rb1_b1 = (const float*)d_in[31];
    const float* rb1_w2 = (const float*)d_in[32];
    const float* rb1_b2 = (const float*)d_in[33];
    const float* rb2_w1 = (const float*)d_in[34];
    const float* rb2_b1 = (const float*)d_in[35];
    const float* rb2_w2 = (const float*)d_in[36];
    const float* rb2_b2 = (const float*)d_in[37];
    const float* g_w  = (const float*)d_in[38];
    const float* g_b  = (const float*)d_in[39];
    const float* th_w = (const float*)d_in[40];
    const float* th_b = (const float*)d_in[41];
    const float* ph_w = (const float*)d_in[42];
    const float* ph_b = (const float*)d_in[43];
    const float* W_w  = (const float*)d_in[44];
    const float* W_b  = (const float*)d_in[45];
    const float* bn_g = (const float*)d_in[46];
    const float* bn_b = (const float*)d_in[47];

    const int NSM = BB * IMG;            // 69696
    float* ws = (float*)d_ws;
    float* du    = ws;
    float* Phi_x = du + NSM;
    float* aubru = Phi_x + BB * MM;
    float* duv   = aubru + BB * MM;
    float* wa    = duv + NSM;
    float* duvw  = wa + NSM;
    float* rr    = duvw + NSM;
    float* bn1a  = rr + NSM;
    float* rr_nl = bn1a + NSM;
    float* xp    = rr_nl + NSM;          // unused
    float* duvww = xp + NSM;             // unused
    float* rr3   = duvww + NSM;                        // B*64*IMG
    float* R7    = rr3 + (size_t)BB * 64 * IMG;
    float* buf_a = R7;
    float* buf_b = R7 + (size_t)BB * 32 * IMG;
    float* agg   = R7;                                  // reuse after bufs dead
    float* b1p   = R7 + (size_t)2 * BB * 32 * IMG;
    float* b2p   = b1p + (size_t)BB * CATT * PIMG;
    float* b3p   = b2p + (size_t)BB * CATT * PIMG;
    float* scores= b3p + (size_t)BB * CATT * PIMG;      // B*81*IMG
    float* ybuf  = scores;                              // reuse (attn dead after k_agg)
    float* PhiWT = scores + (size_t)BB * NPATCH * IMG;  // spare (unused now)
    float* PhiTWT= PhiWT + (size_t)MM * IMG;            // [272][1089]

    const int tot32 = BB * 32 * PP * 3;   // strip-11 threads (Cin=1 convs)
    const int tot64 = BB * 64 * PP * 3;

    hipMemsetAsync(b1p, 0, (size_t)3 * BB * CATT * PIMG * sizeof(float), stream);

    {
        dim3 blk(32, 8);
        dim3 g2(cdiv_i(MM, 32), cdiv_i(IMG, 32));
        k_tr<<<g2, blk, 0, stream>>>(PhiTW, PhiTWT, IMG, MM);
    }

    {
        dim3 gp(BB, 68);
        k_phi2<<<gp, 256, 0, stream>>>(x, PhiW, Phix, ru, mu_p, Phi_x, aubru);
        dim3 gd(cdiv_i(IMG, 64), BB);
        k_duv2<<<gd, 256, 0, stream>>>(x, v_in, PhiTb, PhiTWT, Phi_x, aubru, conv1_w,
                                       beta_p, ls2_p, du, duv, wa);
    }

    dim3 gc(BB, 11);   // banded conv32 grid

    // denoiser
    k_conv3x3<<<cdiv_i(tot32,256),256,0,stream>>>(duv,  head_w, head_b, nullptr, nullptr, buf_a, 1, 32, 0, tot32);
    k_conv32<<<gc,256,0,stream>>>(buf_a, rb1_w1, rb1_b1, nullptr, nullptr, buf_b, 1);
    k_conv32<<<gc,256,0,stream>>>(buf_b, rb1_w2, rb1_b2, buf_a,  nullptr, buf_a, 0);
    k_conv32<<<gc,256,0,stream>>>(buf_a, rb2_w1, rb2_b1, nullptr, nullptr, buf_b, 1);
    k_conv32<<<gc,256,0,stream>>>(buf_b, rb2_w2, rb2_b2, buf_a,  nullptr, buf_a, 0);
    k_tailduvw<<<cdiv_i(NSM,64),256,0,stream>>>(buf_a, tail_w, tail_b, duv, du, v_in, beta_p, duvw, NSM);
    k_convrr<<<cdiv_i(NSM,256),256,0,stream>>>(duvw, conv2_w, r_in, x, xx_in, wa, uu_in,
                                               theta_p, ls_p, bn_g, bn_b, rr, bn1a, NSM);
    k_conv3x3<<<cdiv_i(tot64,256),256,0,stream>>>(bn1a, convG1_w, nullptr, nullptr, nullptr, rr3, 1, 64, 1, tot64);

    // attention
    {
        dim3 gb(cdiv_i(BB * IMG, 256), 3);
        k_b123<<<gb, 256, 0, stream>>>(rr3, g_w, g_b, th_w, th_b, ph_w, ph_b, b1p, b2p, b3p);
    }
    {
        dim3 gs(BB * 5, 6);
        k_scores<<<gs, 128, 0, stream>>>(b1p, b3p, scores);
    }
    k_softmax<<<BB * NPATCH, 256, 0, stream>>>(scores);
    {
        dim3 ga(BB, 2, 9);
        k_agg<<<ga, 256, 0, stream>>>(scores, b2p, agg);
    }
    k_foldW<<<BB * 35, 256, 0, stream>>>(agg, W_w, W_b, rr3, ybuf);
    k_conv1out<<<cdiv_i(NSM,64),256,0,stream>>>(ybuf, convG2_w, rr, rr_nl, 64, NSM);

    // ISTA soft-threshold stage
    k_conv3x3<<<cdiv_i(tot32,256),256,0,stream>>>(rr_nl, convD_w,  nullptr, nullptr, nullptr, buf_a, 1, 32, 0, tot32);
    k_conv32<<<gc,256,0,stream>>>(buf_a, conv1f_w, nullptr, nullptr, nullptr, buf_b, 1);
    k_conv32<<<gc,256,0,stream>>>(buf_b, conv2f_w, nullptr, nullptr, thr_p,   buf_a, 2);
    k_conv32<<<gc,256,0,stream>>>(buf_a, conv1b_w, nullptr, nullptr, nullptr, buf_b, 1);
    k_conv32<<<gc,256,0,stream>>>(buf_b, conv2b_w, nullptr, nullptr, nullptr, buf_a, 0);
    k_conv1out<<<cdiv_i(NSM,64),256,0,stream>>>(buf_a, convG_w, rr_nl, (float*)d_out, 32, NSM);
}